// Round 3
// baseline (644.599 us; speedup 1.0000x reference)
//
#include <hip/hip_runtime.h>
#include <math.h>

#define NEMB 256
#define DIM 64
#define SIGS 128
#define THREADS 512
#define NSIG 131072
#define GRID (NSIG / SIGS)

#define LOG1P50 3.9318256327243257        // np.log1p(50.0), f64
#define INV_MU_F ((float)(1.0 / LOG1P50)) // fp32-rounded scalar, as numpy uses
#define TWO15_F ((float)(2.0 / 15.0))

// dynamic LDS layout (byte offsets) — Dn NOT staged (L2-hot from global)
#define LB_SIG   0          // 32768 B : sig f32 [c][w]
#define LB_XS    32768      // 2048 B  : raw coeffs f32 [4][SIGS] (quantized in-place)
#define LB_QI    34816      // 2048 B  : qi i32 [4][SIGS]
#define LB_RED   36864      // 64 B    : per-wave loss partials (f64)
#define LDS_BYTES 36928

typedef float f2 __attribute__((ext_vector_type(2)));

// One merge step of the 16-lane group argmax reduce. Payload: (bv = masked |h|,
// bh = original h_bar at best, gi = global atom idx). Total order: value desc,
// index asc — identical selection to numpy first-of-max. Pure VALU (DPP).
// row_shr moves data toward HIGHER lanes, so the full group reduction
// accumulates in lane 15 of each 16-group (cf. passing round-1 kernel which
// read lane 63 after its row_shr chain). bound_ctrl zero-injection at row
// edges (lanes 0-3 etc.) never reaches lane 15's merge chain (15<-{11,7},
// both in-range, built from in-range reads at consumption time).
template<int CTRL>
__device__ __forceinline__ void red_step(float& bv, float& bh, int& gi)
{
    float bv2 = __builtin_bit_cast(float,
        __builtin_amdgcn_update_dpp(0, __builtin_bit_cast(int, bv), CTRL, 0xf, 0xf, true));
    float bh2 = __builtin_bit_cast(float,
        __builtin_amdgcn_update_dpp(0, __builtin_bit_cast(int, bh), CTRL, 0xf, 0xf, true));
    int gi2 = __builtin_amdgcn_update_dpp(0, gi, CTRL, 0xf, 0xf, true);
    bool take = (bv2 > bv) || ((bv2 == bv) && (gi2 < gi));
    bv = take ? bv2 : bv;
    bh = take ? bh2 : bh;
    gi = take ? gi2 : gi;
}

// broadcast lane 15 of each 16-group -> all lanes of that group.
// ds_swizzle BitMode: offset = (xor<<10)|(or<<5)|and = (0xF<<5)|0x10 = 0x1F0
// -> src = (lane & 0x10) | 0xF, per 32-half = absolute lanes 15/31/47/63.
__device__ __forceinline__ float swz16_f(float v)
{
    return __builtin_bit_cast(float,
        __builtin_amdgcn_ds_swizzle(__builtin_bit_cast(int, v), 0x01F0));
}
__device__ __forceinline__ int swz16_i(int v)
{
    return __builtin_amdgcn_ds_swizzle(v, 0x01F0);
}

// nrm: fp32, squares rounded individually, sequential sum over c, mirrors np.
// Also zero-initializes the loss accumulator + completion counter.
__global__ void k_normalize(const float* __restrict__ D, float* __restrict__ Dn,
                            double* __restrict__ loss_acc, unsigned int* __restrict__ ctr)
{
#pragma clang fp contract(off)
    int n = threadIdx.x;   // one thread per column, 256 threads
    if (n == 0) { loss_acc[0] = 0.0; ctr[0] = 0u; }
    float ss = 0.0f;
    for (int c = 0; c < DIM; c++) {
        float v = D[c * NEMB + n];
        float sq = v * v;
        ss = ss + sq;
    }
    float nrm = fmaxf(sqrtf(ss), 1e-10f);
    for (int c = 0; c < DIM; c++)
        Dn[c * NEMB + n] = D[c * NEMB + n] / nrm;
}

// G = Dn^T Dn: fp32, fused-FMA sequential over k ascending
__global__ void k_gram(const float* __restrict__ Dn, float* __restrict__ G)
{
    __shared__ float coli[DIM];
    int i = blockIdx.x, j = threadIdx.x;
    if (j < DIM) coli[j] = Dn[j * NEMB + i];
    __syncthreads();
    float s = 0.0f;
#pragma unroll
    for (int c = 0; c < DIM; c++) s = fmaf(coli[c], Dn[c * NEMB + j], s);
    G[i * NEMB + j] = s;
}

// mu-law quantize+decode, all fp32, numpy op-for-op (no fusion)
__device__ __forceinline__ float quant_decode(float coeff)
{
#pragma clang fp contract(off)
    float c = fminf(fmaxf(coeff, -3.0f), 3.0f) / 3.0f;
    float ac = fabsf(c);
    float sgn = (c > 0.0f) ? 1.0f : ((c < 0.0f) ? -1.0f : 0.0f);
    float l = log1pf(ac * 50.0f);
    float enc = (sgn * l) * INV_MU_F;
    float scaled = (enc + 1.0f) * 7.5f;
    int bin = (int)rintf(scaled);              // round-half-even == np.round
    bin = bin < 0 ? 0 : (bin > 15 ? 15 : bin);
    float t = (float)bin * TWO15_F;
    float zv = t - 1.0f;
    float az = fabsf(zv);
    float sz = (zv > 0.0f) ? 1.0f : ((zv < 0.0f) ? -1.0f : 0.0f);
    float e = expm1f(az / INV_MU_F);
    return (sz * (e / 50.0f)) * 3.0f;
}

// k_omp: 16 lanes per signal (lane 16g+q owns atoms 16q..16q+15 of signal g),
// 4 signals per wave-quad, 4 quads per wave = 16 signals/wave.
//  - argmax: 16-elem local scan tracking (|h|, h_bar, gidx) + 4 DPP merge
//    steps (quad_perm ^1,^2 + row_shr 4,8 -> lane 15) + ds_swizzle broadcast.
//    No ballot / ffsll / readlane / select-trees.
//  - Cholesky + solves: ONE instruction stream serves 4 signals (operands
//    group-uniform; every lane computes its group's recurrence).
//  - Gs = G[Iv_j][idx] scalar loads (L1-hot rows); residual rows cached
//    in regs per group-quarter (16 cols/lane), loads issued pre-chol.
//  - per-element fp sequences identical to the previous passing kernel.
__launch_bounds__(THREADS, 4)
__global__ void k_omp(const float* __restrict__ z,
                      const float* __restrict__ Dn_g,
                      const float* __restrict__ G,
                      double* __restrict__ loss_acc,
                      unsigned int* __restrict__ ctr,
                      float* __restrict__ zq,
                      float* __restrict__ loss_out)
{
#pragma clang fp contract(off)
    extern __shared__ char smem[];
    float* sig = (float*)(smem + LB_SIG);
    float* xsv = (float*)(smem + LB_XS);
    int* qi = (int*)(smem + LB_QI);
    double* red = (double*)(smem + LB_RED);

    int tid = threadIdx.x;
    int lane = tid & 63;
    int wid = tid >> 6;
    int q = lane & 15;        // lane within 16-group
    int g = lane >> 4;        // group = signal slot (0..3)
    int q16 = q << 4;         // first atom this lane owns

    long sbase = (long)blockIdx.x * SIGS;   // 128 consecutive pixels, one batch b
    int b = (int)(sbase >> 12);
    int pl0 = (int)(sbase & 4095);
    const float* zb = z + ((size_t)b << 18) + pl0;
    // stage z_e -> sig[c][w], coalesced along w
    {
        int w = tid & (SIGS - 1);
        int gg = tid >> 7;
#pragma unroll
        for (int i = 0; i < 16; i++) {
            int c = gg * 16 + i;
            sig[c * SIGS + w] = zb[(size_t)c * 4096 + w];
        }
    }
    __syncthreads();

    for (int quad = 0; quad < 4; quad++) {
        int s = wid * 16 + quad * 4 + g;
        // ---- h_bar[s][q16..q16+15]: fp32 fmaf sequential over c ascending,
        //      per-element identical to previous version (lane remap only).
        //      sig read is a 4-address broadcast; Dn f4 reads are L1-hot.
        f2 hb[8];
#pragma unroll
        for (int i = 0; i < 8; i++) hb[i] = (f2){0.0f, 0.0f};
#pragma unroll 4
        for (int c = 0; c < DIM; c++) {
            float xc = sig[c * SIGS + s];
            const float4* dp = (const float4*)(Dn_g + c * NEMB + q16);
            float4 d0 = dp[0], d1 = dp[1], d2 = dp[2], d3 = dp[3];
            f2 sv = {xc, xc};
            hb[0] = __builtin_elementwise_fma(sv, (f2){d0.x, d0.y}, hb[0]);
            hb[1] = __builtin_elementwise_fma(sv, (f2){d0.z, d0.w}, hb[1]);
            hb[2] = __builtin_elementwise_fma(sv, (f2){d1.x, d1.y}, hb[2]);
            hb[3] = __builtin_elementwise_fma(sv, (f2){d1.z, d1.w}, hb[3]);
            hb[4] = __builtin_elementwise_fma(sv, (f2){d2.x, d2.y}, hb[4]);
            hb[5] = __builtin_elementwise_fma(sv, (f2){d2.z, d2.w}, hb[5]);
            hb[6] = __builtin_elementwise_fma(sv, (f2){d3.x, d3.y}, hb[6]);
            hb[7] = __builtin_elementwise_fma(sv, (f2){d3.z, d3.w}, hb[7]);
        }

        // scan values = masked |h| (mask empty at kk=0)
        float scanv[16];
#pragma unroll
        for (int j = 0; j < 16; j++) scanv[j] = fabsf(hb[j >> 1][j & 1]);

        int msel = 0;                       // local selected-atom bitmask
        float L10, L11, L20, L21, L22, L30, L31, L32, L33;
        float y0, y1, y2, y3;
        float x0 = 0.f, x1 = 0.f, x2 = 0.f, x3 = 0.f;
        int Iv0 = 0, Iv1 = 0, Iv2 = 0, Iv3 = 0;
        f2 gr[3][8];                        // cached G rows (this lane's 16 cols)

#pragma unroll
        for (int kk = 0; kk < 4; kk++) {
            // ---- local scan: strict > ascending = first-of-max within lane ----
            float bv = -1.0f, bh = 0.0f;
            int gi = 0;
#pragma unroll
            for (int j = 0; j < 16; j++) {
                float av = scanv[j];
                bool t = av > bv;
                bv = t ? av : bv;
                bh = t ? hb[j >> 1][j & 1] : bh;
                gi = t ? (q16 + j) : gi;
            }
            // ---- 16-lane group reduce (max value, then smallest gidx) ----
            red_step<0xB1>(bv, bh, gi);    // quad_perm [1,0,3,2] : lane^1
            red_step<0x4E>(bv, bh, gi);    // quad_perm [2,3,0,1] : lane^2
            red_step<0x114>(bv, bh, gi);   // row_shr:4
            red_step<0x118>(bv, bh, gi);   // row_shr:8  -> lane 15 (mod 16) full
            bh = swz16_f(bh);              // broadcast group-lane15 -> group
            gi = swz16_i(gi);
            float hsel = bh;               // original h_bar[idx]

            // ---- issue this round's loads early (hidden under chol/solves) ----
            float Gs0 = 0.f, Gs1 = 0.f, Gs2 = 0.f;
            if (kk > 0) Gs0 = G[(Iv0 << 8) + gi];   // G[Iv_j][idx], L1-hot
            if (kk > 1) Gs1 = G[(Iv1 << 8) + gi];
            if (kk > 2) Gs2 = G[(Iv2 << 8) + gi];
            if (kk < 3) {                  // residual row cache: 16 cols/lane
                const float4* grp = (const float4*)(G + ((size_t)gi << 8) + q16);
                float4 ra = grp[0], rb = grp[1], rc = grp[2], rd = grp[3];
                gr[kk][0] = (f2){ra.x, ra.y};  gr[kk][1] = (f2){ra.z, ra.w};
                gr[kk][2] = (f2){rb.x, rb.y};  gr[kk][3] = (f2){rb.z, rb.w};
                gr[kk][4] = (f2){rc.x, rc.y};  gr[kk][5] = (f2){rc.z, rc.w};
                gr[kk][6] = (f2){rd.x, rd.y};  gr[kk][7] = (f2){rd.z, rd.w};
            }
            // ---- mask update (owner lane clears its local bit) ----
            {
                int bit = 1 << (gi & 15);
                msel |= ((gi >> 4) == q) ? bit : 0;
            }
            if (kk == 0) Iv0 = gi;
            if (kk == 1) Iv1 = gi;
            if (kk == 2) Iv2 = gi;
            if (kk == 3) Iv3 = gi;

            // ---- Cholesky row update (op-for-op as previous passing version;
            //      divides by L00==1 removed, exact identity) ----
            if (kk == 1) {
                float w0 = Gs0;
                float ss = w0 * w0;
                float om = 1.0f - ss;
                L10 = w0;
                L11 = sqrtf(fmaxf(om, 1e-12f));
            }
            if (kk == 2) {
                float w0 = Gs0;
                float t2 = Gs1 - L10 * w0;
                float w1 = t2 / L11;
                float ss = w0 * w0;
                float p = w1 * w1; ss = ss + p;
                float om = 1.0f - ss;
                L20 = w0; L21 = w1;
                L22 = sqrtf(fmaxf(om, 1e-12f));
            }
            if (kk == 3) {
                float w0 = Gs0;
                float t2 = Gs1 - L10 * w0;
                float w1 = t2 / L11;
                float acc = L20 * w0;
                float p = L21 * w1; acc = acc + p;
                float t3 = Gs2 - acc;
                float w2 = t3 / L22;
                float ss = w0 * w0;
                p = w1 * w1; ss = ss + p;
                p = w2 * w2; ss = ss + p;
                float om = 1.0f - ss;
                L30 = w0; L31 = w1; L32 = w2;
                L33 = sqrtf(fmaxf(om, 1e-12f));
            }
            // ---- forward solve, incremental (row kk only) ----
            if (kk == 0) y0 = hsel;
            if (kk == 1) { float a = L10 * y0; y1 = (hsel - a) / L11; }
            if (kk == 2) { float a = L20 * y0; float p = L21 * y1; a = a + p;
                           y2 = (hsel - a) / L22; }
            if (kk == 3) { float a = L30 * y0; float p = L31 * y1; a = a + p;
                           p = L32 * y2; a = a + p;
                           y3 = (hsel - a) / L33; }
            // ---- backward solve L^T x = y (full, cc ascending) ----
            if (kk == 0) { x0 = y0; }
            if (kk == 1) {
                x1 = y1 / L11;
                float a = L10 * x1;
                x0 = y0 - a;
            }
            if (kk == 2) {
                x2 = y2 / L22;
                float a = L21 * x2;
                x1 = (y1 - a) / L11;
                a = L10 * x1;
                float p = L20 * x2; a = a + p;
                x0 = y0 - a;
            }
            if (kk == 3) {
                x3 = y3 / L33;
                float a = L32 * x3;
                x2 = (y2 - a) / L22;
                a = L21 * x2;
                float p = L31 * x3; a = a + p;
                x1 = (y1 - a) / L11;
                a = L10 * x1;
                p = L20 * x2; a = a + p;
                p = L30 * x3; a = a + p;
                x0 = y0 - a;
            }
            // ---- residual (mul+add ascending jj, no fma) + next scan values ----
            if (kk < 3) {
                f2 xv0 = {x0, x0};
                f2 xv1 = {x1, x1};
                f2 xv2 = {x2, x2};
#pragma unroll
                for (int i = 0; i < 8; i++) {
                    f2 bsum = xv0 * gr[0][i];            // == 0 + p (sign-safe)
                    if (kk > 0) { f2 pp = xv1 * gr[1][i]; bsum = bsum + pp; }
                    if (kk > 1) { f2 pp = xv2 * gr[2][i]; bsum = bsum + pp; }
                    f2 hres = hb[i] - bsum;
                    float a0 = fabsf(hres[0]);
                    float a1 = fabsf(hres[1]);
                    scanv[2 * i]     = (msel & (1 << (2 * i)))     ? 0.0f : a0;
                    scanv[2 * i + 1] = (msel & (1 << (2 * i + 1))) ? 0.0f : a1;
                }
            }
        }
        // group-lane 0 writes the signal's raw coeffs + support
        if (q == 0) {
            xsv[0 * SIGS + s] = x0; xsv[1 * SIGS + s] = x1;
            xsv[2 * SIGS + s] = x2; xsv[3 * SIGS + s] = x3;
            qi[0 * SIGS + s] = Iv0; qi[1 * SIGS + s] = Iv1;
            qi[2 * SIGS + s] = Iv2; qi[3 * SIGS + s] = Iv3;
        }
    }
    __syncthreads();

    // thread-parallel mu-law quantize of all 512 coeffs
    {
        int jq = tid >> 7;
        int wq = tid & (SIGS - 1);
        xsv[jq * SIGS + wq] = quant_decode(xsv[jq * SIGS + wq]);
    }
    __syncthreads();

    // store phase: recon (einsum order: mul+add, k ascending, no fma),
    // z_q = z_e + (recon - z_e), loss accumulated in f64
    double lsum = 0.0;
    float* zqb = zq + ((size_t)b << 18) + pl0;
    {
        int w = tid & (SIGS - 1);
        int gg = tid >> 7;
        float q0 = xsv[0 * SIGS + w], q1 = xsv[1 * SIGS + w];
        float q2 = xsv[2 * SIGS + w], q3 = xsv[3 * SIGS + w];
        int i0 = qi[0 * SIGS + w], i1 = qi[1 * SIGS + w];
        int i2 = qi[2 * SIGS + w], i3 = qi[3 * SIGS + w];
#pragma unroll
        for (int ci = 0; ci < 16; ci++) {
            int c = gg * 16 + ci;
            const float* dr = Dn_g + c * NEMB;
            float p0 = q0 * dr[i0];
            float p1 = q1 * dr[i1];
            float p2 = q2 * dr[i2];
            float p3 = q3 * dr[i3];
            float r = p0 + p1;
            r = r + p2;
            r = r + p3;
            float zev = sig[c * SIGS + w];
            float d = r - zev;
            float zqv = zev + d;           // z_q = z_e + (recon - z_e)
            lsum += (double)d * (double)d;
            zqb[(size_t)c * 4096 + w] = zqv;
        }
    }
#pragma unroll
    for (int off = 32; off > 0; off >>= 1) lsum += __shfl_xor(lsum, off);
    if (lane == 0) red[wid] = lsum;
    __syncthreads();
    if (tid == 0) {
        double t = 0.0;
#pragma unroll
        for (int i = 0; i < 8; i++) t += red[i];
        atomicAdd(loss_acc, t);
        __threadfence();
        unsigned int done = atomicAdd(ctr, 1u);
        if (done == GRID - 1) {
            double m = atomicAdd(loss_acc, 0.0) / 8388608.0;
            loss_out[0] = (float)(m + 0.25 * m);
        }
    }
}

extern "C" void kernel_launch(void* const* d_in, const int* in_sizes, int n_in,
                              void* d_out, int out_size, void* d_ws, size_t ws_size,
                              hipStream_t stream)
{
    const float* z = (const float*)d_in[0];
    const float* D = (const float*)d_in[1];
    float* out = (float*)d_out;
    char* ws = (char*)d_ws;
    double* loss_acc = (double*)ws;              // 8 B
    unsigned int* ctr = (unsigned int*)(ws + 8); // 4 B
    float* Dn = (float*)(ws + 256);              // 64x256 f32
    float* G = (float*)(ws + 256 + 65536);       // 256x256 f32

    k_normalize<<<1, NEMB, 0, stream>>>(D, Dn, loss_acc, ctr);
    k_gram<<<NEMB, NEMB, 0, stream>>>(Dn, G);
    hipFuncSetAttribute(reinterpret_cast<const void*>(k_omp),
                        hipFuncAttributeMaxDynamicSharedMemorySize, LDS_BYTES);
    k_omp<<<GRID, THREADS, LDS_BYTES, stream>>>(z, Dn, G, loss_acc, ctr, out, out + 8388608);
    (void)in_sizes; (void)n_in; (void)out_size; (void)ws_size;
}

// Round 4
// 358.359 us; speedup vs baseline: 1.7988x; 1.7988x over previous
//
#include <hip/hip_runtime.h>
#include <math.h>

#define NEMB 256
#define DIM 64
#define SIGS 128
#define THREADS 512
#define NSIG 131072
#define GRID (NSIG / SIGS)

#define LOG1P50 3.9318256327243257        // np.log1p(50.0), f64
#define INV_MU_F ((float)(1.0 / LOG1P50)) // fp32-rounded scalar, as numpy uses
#define TWO15_F ((float)(2.0 / 15.0))

// dynamic LDS layout (byte offsets) — Dn NOT staged (L2-hot from global)
// 37 KB/block -> 4 blocks/CU co-resident (148 KB of 160 KB LDS)
#define LB_SIG   0          // 32768 B : sig f32 [c][w]
#define LB_XS    32768      // 2048 B  : raw coeffs f32 [4][SIGS] (quantized in-place)
#define LB_QI    34816      // 2048 B  : qi i32 [4][SIGS]
#define LB_RED   36864      // 64 B    : per-wave loss partials (f64)
#define LDS_BYTES 36928

typedef float f2 __attribute__((ext_vector_type(2)));

__device__ __forceinline__ float rdlane_f(float v, int lane)
{
    return __builtin_bit_cast(float, __builtin_amdgcn_readlane(__builtin_bit_cast(int, v), lane));
}

template<int CTRL>
__device__ __forceinline__ float dpp_fmax(float m)
{
    int sh = __builtin_amdgcn_update_dpp(0, __builtin_bit_cast(int, m), CTRL, 0xf, 0xf, true);
    return fmaxf(m, __builtin_bit_cast(float, sh));
}

// wave-wide max of non-negative values; valid in lane 63. Pure VALU (DPP).
__device__ __forceinline__ float wave_max_nn(float v)
{
    v = dpp_fmax<0x111>(v);   // row_shr:1
    v = dpp_fmax<0x112>(v);   // row_shr:2
    v = dpp_fmax<0x114>(v);   // row_shr:4
    v = dpp_fmax<0x118>(v);   // row_shr:8  -> lane 15/31/47/63 = row max
    v = dpp_fmax<0x142>(v);   // row_bcast:15 -> lane 31/63 = half max
    v = dpp_fmax<0x143>(v);   // row_bcast:31 -> lane 63 = wave max
    return v;
}

// nrm: fp32, squares rounded individually, sequential sum over c, mirrors np.
// Also zero-initializes the loss accumulator + completion counter.
__global__ void k_normalize(const float* __restrict__ D, float* __restrict__ Dn,
                            double* __restrict__ loss_acc, unsigned int* __restrict__ ctr)
{
#pragma clang fp contract(off)
    int n = threadIdx.x;   // one thread per column, 256 threads
    if (n == 0) { loss_acc[0] = 0.0; ctr[0] = 0u; }
    float ss = 0.0f;
    for (int c = 0; c < DIM; c++) {
        float v = D[c * NEMB + n];
        float sq = v * v;
        ss = ss + sq;
    }
    float nrm = fmaxf(sqrtf(ss), 1e-10f);
    for (int c = 0; c < DIM; c++)
        Dn[c * NEMB + n] = D[c * NEMB + n] / nrm;
}

// G = Dn^T Dn: fp32, fused-FMA sequential over k ascending
__global__ void k_gram(const float* __restrict__ Dn, float* __restrict__ G)
{
    __shared__ float coli[DIM];
    int i = blockIdx.x, j = threadIdx.x;
    if (j < DIM) coli[j] = Dn[j * NEMB + i];
    __syncthreads();
    float s = 0.0f;
#pragma unroll
    for (int c = 0; c < DIM; c++) s = fmaf(coli[c], Dn[c * NEMB + j], s);
    G[i * NEMB + j] = s;
}

// mu-law quantize+decode, all fp32, numpy op-for-op (no fusion)
__device__ __forceinline__ float quant_decode(float coeff)
{
#pragma clang fp contract(off)
    float c = fminf(fmaxf(coeff, -3.0f), 3.0f) / 3.0f;
    float ac = fabsf(c);
    float sgn = (c > 0.0f) ? 1.0f : ((c < 0.0f) ? -1.0f : 0.0f);
    float l = log1pf(ac * 50.0f);
    float enc = (sgn * l) * INV_MU_F;
    float scaled = (enc + 1.0f) * 7.5f;
    int bin = (int)rintf(scaled);              // round-half-even == np.round
    bin = bin < 0 ? 0 : (bin > 15 ? 15 : bin);
    float t = (float)bin * TWO15_F;
    float zv = t - 1.0f;
    float az = fabsf(zv);
    float sz = (zv > 0.0f) ? 1.0f : ((zv < 0.0f) ? -1.0f : 0.0f);
    float e = expm1f(az / INV_MU_F);
    return (sz * (e / 50.0f)) * 3.0f;
}

// TWO signals' OMP (K=4) per call: argmax/residual distributed over all
// 64 lanes per signal (4 atoms/lane), wave-uniform Cholesky + triangular
// solves run ONCE on half-selected operands: lanes 0-31 compute signal A's
// recurrence, lanes 32-63 signal B's. Bit-identical per-signal arithmetic.
__device__ __forceinline__ void omp_pair(const f2* hbA_in, const f2* hbB_in,
                                         int lane, int hi,
                                         const float* __restrict__ G,
                                         float* __restrict__ xsv,
                                         int* __restrict__ qi, int sA)
{
#pragma clang fp contract(off)
    f2 hbsiA[2] = {hbA_in[0], hbA_in[1]};
    f2 hbsiB[2] = {hbB_in[0], hbB_in[1]};
    f2 hA[2] = {hbsiA[0], hbsiA[1]};
    f2 hB[2] = {hbsiB[0], hbsiB[1]};
    f2 GrA[3][2], GrB[3][2];
    float Lm[4][4];
    int IvA[4], IvB[4];
    float y[4], xs[4];
    int m4A = 0, m4B = 0;
#pragma unroll
    for (int kk = 0; kk < 4; kk++) {
        // ---- per-lane best of own 4 atoms, both signals (independent ILP) ----
        float bvA = -1.0f, bvB = -1.0f;
        int bjA = 0, bjB = 0;
#pragma unroll
        for (int j = 0; j < 4; j++) {
            float vA_ = (m4A & (1 << j)) ? 0.0f : fabsf(hA[j >> 1][j & 1]);
            if (vA_ > bvA) { bvA = vA_; bjA = j; }
            float vB_ = (m4B & (1 << j)) ? 0.0f : fabsf(hB[j >> 1][j & 1]);
            if (vB_ > bvB) { bvB = vB_; bjB = j; }
        }
        // ---- wave max via DPP (value only), two independent chains ----
        float mA = wave_max_nn(bvA);
        float mB = wave_max_nn(bvB);
        float vmaxA = rdlane_f(mA, 63);
        float vmaxB = rdlane_f(mB, 63);
        // ---- first lane holding the max = numpy first-index tie-break ----
        unsigned long long ballA = __ballot(bvA == vmaxA);
        unsigned long long ballB = __ballot(bvB == vmaxB);
        int ownerA = __ffsll((long long)ballA) - 1;
        int ownerB = __ffsll((long long)ballB) - 1;
        int bjAo = __builtin_amdgcn_readlane(bjA, ownerA);
        int bjBo = __builtin_amdgcn_readlane(bjB, ownerB);
        int idxA = 4 * ownerA + bjAo;
        int idxB = 4 * ownerB + bjBo;
        m4A |= (lane == ownerA) ? (1 << bjAo) : 0;
        m4B |= (lane == ownerB) ? (1 << bjBo) : 0;
        IvA[kk] = idxA; IvB[kk] = idxB;
        // ---- original h_bar value at selected atom ----
        float tvA = hbsiA[0][0];
        tvA = (bjA == 1) ? hbsiA[0][1] : tvA;
        tvA = (bjA == 2) ? hbsiA[1][0] : tvA;
        tvA = (bjA == 3) ? hbsiA[1][1] : tvA;
        float tvB = hbsiB[0][0];
        tvB = (bjB == 1) ? hbsiB[0][1] : tvB;
        tvB = (bjB == 2) ? hbsiB[1][0] : tvB;
        tvB = (bjB == 3) ? hbsiB[1][1] : tvB;
        float hselA = rdlane_f(tvA, ownerA);
        float hselB = rdlane_f(tvB, ownerB);
        float hsel = hi ? hselB : hselA;
        // ---- cache G rows for this atom (float4/lane, coalesced, L2-hot) ----
        if (kk < 3) {
            const float4 ga = *(const float4*)(G + ((size_t)idxA << 8) + 4 * lane);
            const float4 gb = *(const float4*)(G + ((size_t)idxB << 8) + 4 * lane);
            GrA[kk][0].x = ga.x; GrA[kk][0].y = ga.y;
            GrA[kk][1].x = ga.z; GrA[kk][1].y = ga.w;
            GrB[kk][0].x = gb.x; GrB[kk][0].y = gb.y;
            GrB[kk][1].x = gb.z; GrB[kk][1].y = gb.w;
        }
        // ---- Cholesky row update (halves: A on lanes 0-31, B on 32-63) ----
        if (kk > 0) {
            float Gs[3], w[3];
#pragma unroll
            for (int j = 0; j < 3; j++)
                if (j < kk) {
                    // G[Iv[j]][idx] == element bj_o of cached row j at lane owner
                    float eA = GrA[j][0][0];
                    eA = (bjAo == 1) ? GrA[j][0][1] : eA;
                    eA = (bjAo == 2) ? GrA[j][1][0] : eA;
                    eA = (bjAo == 3) ? GrA[j][1][1] : eA;
                    float eB = GrB[j][0][0];
                    eB = (bjBo == 1) ? GrB[j][0][1] : eB;
                    eB = (bjBo == 2) ? GrB[j][1][0] : eB;
                    eB = (bjBo == 3) ? GrB[j][1][1] : eB;
                    float gA = rdlane_f(eA, ownerA);
                    float gB = rdlane_f(eB, ownerB);
                    Gs[j] = hi ? gB : gA;
                }
#pragma unroll
            for (int r = 0; r < 3; r++) {
                if (r < kk) {
                    float acc = 0.0f;
#pragma unroll
                    for (int cc = 0; cc < 3; cc++)
                        if (cc < r) { float p = Lm[r][cc] * w[cc]; acc = acc + p; }
                    float t2 = Gs[r] - acc;
                    w[r] = (r == 0) ? t2 : t2 / Lm[r][r];   // L[0][0]==1: exact
                }
            }
            float ssum = 0.0f;
#pragma unroll
            for (int j = 0; j < 3; j++)
                if (j < kk) { float p = w[j] * w[j]; ssum = ssum + p; }
            float om = 1.0f - ssum;
            float wc = sqrtf(fmaxf(om, 1e-12f));
#pragma unroll
            for (int cc = 0; cc < 3; cc++)
                if (cc < kk) Lm[kk][cc] = w[cc];
            Lm[kk][kk] = wc;
        } else {
            Lm[0][0] = 1.0f;
        }
        // ---- forward solve, incremental: only row kk is new ----
        {
            float acc = 0.0f;
#pragma unroll
            for (int cc = 0; cc < 3; cc++)
                if (cc < kk) { float p = Lm[kk][cc] * y[cc]; acc = acc + p; }
            float t2 = hsel - acc;
            y[kk] = (kk == 0) ? t2 : t2 / Lm[kk][kk];
        }
        // ---- backward solve L^T x = y (full, sum ascending c>r) ----
#pragma unroll
        for (int r = 3; r >= 0; r--) {
            if (r <= kk) {
                float acc = 0.0f;
#pragma unroll
                for (int cc = 0; cc < 4; cc++)
                    if (cc > r && cc <= kk) { float p = Lm[cc][r] * xs[cc]; acc = acc + p; }
                float t2 = y[r] - acc;
                xs[r] = (r == 0) ? t2 : t2 / Lm[r][r];      // L[0][0]==1: exact
            }
        }
        // ---- residual: h = h_bar - einsum(x, G[I]) (mul+add, k ascending) ----
        if (kk < 3) {
            float xsA[4], xsB[4];
#pragma unroll
            for (int j = 0; j < 4; j++)
                if (j <= kk) {
                    xsA[j] = rdlane_f(xs[j], 0);
                    xsB[j] = rdlane_f(xs[j], 32);
                }
#pragma unroll
            for (int jp = 0; jp < 2; jp++) {
                f2 bsA = {0.0f, 0.0f};
                f2 bsB = {0.0f, 0.0f};
#pragma unroll
                for (int jj = 0; jj < 3; jj++)
                    if (jj <= kk) {
                        f2 xa = {xsA[jj], xsA[jj]};
                        f2 xb = {xsB[jj], xsB[jj]};
                        f2 pA = xa * GrA[jj][jp];
                        bsA = bsA + pA;
                        f2 pB = xb * GrB[jj][jp];
                        bsB = bsB + pB;
                    }
                hA[jp] = hbsiA[jp] - bsA;
                hB[jp] = hbsiB[jp] - bsB;
            }
        }
    }
    // lane 0 writes signal A, lane 32 writes signal B
    if ((lane & 31) == 0) {
        int s = sA + hi;
#pragma unroll
        for (int j = 0; j < 4; j++) {
            xsv[j * SIGS + s] = xs[j];   // raw coeff; quantized later in parallel
            qi[j * SIGS + s] = hi ? IvB[j] : IvA[j];
        }
    }
}

// __launch_bounds__(512, 8): 8 waves/EU min -> 4 blocks/CU co-resident
// (LDS 37KB x 4 = 148KB <= 160KB; compiler already fit 64 VGPR under the
// looser (512,4) bound, so the 64-VGPR cap introduces no new spills).
// Round-1 measured chain-latency-bound at VALUBusy 60% with 2 blocks/CU;
// doubling resident waves is pure latency hiding, zero numeric change.
__launch_bounds__(THREADS, 8)
__global__ void k_omp(const float* __restrict__ z,
                      const float* __restrict__ Dn_g,
                      const float* __restrict__ G,
                      double* __restrict__ loss_acc,
                      unsigned int* __restrict__ ctr,
                      float* __restrict__ zq,
                      float* __restrict__ loss_out)
{
    extern __shared__ char smem[];
    float* sig = (float*)(smem + LB_SIG);
    float* xsv = (float*)(smem + LB_XS);
    int* qi = (int*)(smem + LB_QI);
    double* red = (double*)(smem + LB_RED);

    int tid = threadIdx.x;
    int lane = tid & 63;
    int hi = lane >> 5;
    int wid = tid >> 6;

    long sbase = (long)blockIdx.x * SIGS;   // 128 consecutive pixels, one batch b
    int b = (int)(sbase >> 12);
    int pl0 = (int)(sbase & 4095);
    const float* zb = z + ((size_t)b << 18) + pl0;
    // stage z_e -> sig[c][w], coalesced along w
    {
        int w = tid & (SIGS - 1);
        int g = tid >> 7;
#pragma unroll
        for (int i = 0; i < 16; i++) {
            int c = g * 16 + i;
            sig[c * SIGS + w] = zb[(size_t)c * 4096 + w];
        }
    }
    __syncthreads();

    // each wave: 16 signals in 2 groups of 8; h_bar = X^T Dn, fp32 fused-FMA
    // sequential over c ascending, packed as float2 -> v_pk_fma_f32
    // (elementwise-identical fma chains). Dn read from global (L1/L2-hot).
    for (int g2 = 0; g2 < 2; g2++) {
        int s0 = wid * 16 + g2 * 8;
        f2 hb[8][2];
#pragma unroll
        for (int a = 0; a < 8; a++) {
            hb[a][0] = (f2){0.0f, 0.0f};
            hb[a][1] = (f2){0.0f, 0.0f};
        }
#pragma unroll 8
        for (int c = 0; c < DIM; c++) {
            float4 sva = *(const float4*)(sig + c * SIGS + s0);
            float4 svb = *(const float4*)(sig + c * SIGS + s0 + 4);
            float s8[8] = {sva.x, sva.y, sva.z, sva.w, svb.x, svb.y, svb.z, svb.w};
            float4 dv = *(const float4*)(Dn_g + c * NEMB + 4 * lane);
            f2 d0; d0.x = dv.x; d0.y = dv.y;
            f2 d1; d1.x = dv.z; d1.y = dv.w;
#pragma unroll
            for (int a = 0; a < 8; a++) {
                f2 sa = {s8[a], s8[a]};
                hb[a][0] = __builtin_elementwise_fma(sa, d0, hb[a][0]);
                hb[a][1] = __builtin_elementwise_fma(sa, d1, hb[a][1]);
            }
        }
#pragma unroll
        for (int p = 0; p < 4; p++)
            omp_pair(hb[2 * p], hb[2 * p + 1], lane, hi, G, xsv, qi, s0 + 2 * p);
    }
    __syncthreads();

    // thread-parallel mu-law quantize of all 512 coeffs
    {
        int jq = tid >> 7;
        int wq = tid & (SIGS - 1);
        xsv[jq * SIGS + wq] = quant_decode(xsv[jq * SIGS + wq]);
    }
    __syncthreads();

    // store phase: recon (einsum order: mul+add, k ascending, no fma),
    // z_q = z_e + (recon - z_e), loss accumulated in f64
    double lsum = 0.0;
    float* zqb = zq + ((size_t)b << 18) + pl0;
    {
#pragma clang fp contract(off)
        int w = tid & (SIGS - 1);
        int g = tid >> 7;
        float q0 = xsv[0 * SIGS + w], q1 = xsv[1 * SIGS + w];
        float q2 = xsv[2 * SIGS + w], q3 = xsv[3 * SIGS + w];
        int i0 = qi[0 * SIGS + w], i1 = qi[1 * SIGS + w];
        int i2 = qi[2 * SIGS + w], i3 = qi[3 * SIGS + w];
#pragma unroll
        for (int ci = 0; ci < 16; ci++) {
            int c = g * 16 + ci;
            const float* dr = Dn_g + c * NEMB;
            float p0 = q0 * dr[i0];
            float p1 = q1 * dr[i1];
            float p2 = q2 * dr[i2];
            float p3 = q3 * dr[i3];
            float r = p0 + p1;
            r = r + p2;
            r = r + p3;
            float zev = sig[c * SIGS + w];
            float d = r - zev;
            float zqv = zev + d;           // z_q = z_e + (recon - z_e)
            lsum += (double)d * (double)d;
            zqb[(size_t)c * 4096 + w] = zqv;
        }
    }
#pragma unroll
    for (int off = 32; off > 0; off >>= 1) lsum += __shfl_xor(lsum, off);
    if (lane == 0) red[wid] = lsum;
    __syncthreads();
    if (tid == 0) {
        double t = 0.0;
#pragma unroll
        for (int i = 0; i < 8; i++) t += red[i];
        atomicAdd(loss_acc, t);
        __threadfence();
        unsigned int done = atomicAdd(ctr, 1u);
        if (done == GRID - 1) {
            double m = atomicAdd(loss_acc, 0.0) / 8388608.0;
            loss_out[0] = (float)(m + 0.25 * m);
        }
    }
}

extern "C" void kernel_launch(void* const* d_in, const int* in_sizes, int n_in,
                              void* d_out, int out_size, void* d_ws, size_t ws_size,
                              hipStream_t stream)
{
    const float* z = (const float*)d_in[0];
    const float* D = (const float*)d_in[1];
    float* out = (float*)d_out;
    char* ws = (char*)d_ws;
    double* loss_acc = (double*)ws;              // 8 B
    unsigned int* ctr = (unsigned int*)(ws + 8); // 4 B
    float* Dn = (float*)(ws + 256);              // 64x256 f32
    float* G = (float*)(ws + 256 + 65536);       // 256x256 f32

    k_normalize<<<1, NEMB, 0, stream>>>(D, Dn, loss_acc, ctr);
    k_gram<<<NEMB, NEMB, 0, stream>>>(Dn, G);
    hipFuncSetAttribute(reinterpret_cast<const void*>(k_omp),
                        hipFuncAttributeMaxDynamicSharedMemorySize, LDS_BYTES);
    k_omp<<<GRID, THREADS, LDS_BYTES, stream>>>(z, Dn, G, loss_acc, ctr, out, out + 8388608);
    (void)in_sizes; (void)n_in; (void)out_size; (void)ws_size;
}

// Round 5
// 312.021 us; speedup vs baseline: 2.0659x; 1.1485x over previous
//
#include <hip/hip_runtime.h>
#include <math.h>

#define NEMB 256
#define DIM 64
#define SIGS 128
#define THREADS 512
#define NSIG 131072
#define GRID (NSIG / SIGS)

#define LOG1P50 3.9318256327243257        // np.log1p(50.0), f64
#define INV_MU_F ((float)(1.0 / LOG1P50)) // fp32-rounded scalar, as numpy uses
#define TWO15_F ((float)(2.0 / 15.0))

// dynamic LDS layout (byte offsets) — Dn NOT staged (L2-hot from global)
// 37 KB/block -> up to 4 blocks/CU by LDS; VGPR (64) caps us at 3 blocks/CU
#define LB_SIG   0          // 32768 B : sig f32 [c][w]
#define LB_XS    32768      // 2048 B  : raw coeffs f32 [4][SIGS] (quantized in-place)
#define LB_QI    34816      // 2048 B  : qi i32 [4][SIGS]
#define LB_RED   36864      // 64 B    : per-wave loss partials (f64)
#define LDS_BYTES 36928

typedef float f2 __attribute__((ext_vector_type(2)));

__device__ __forceinline__ float rdlane_f(float v, int lane)
{
    return __builtin_bit_cast(float, __builtin_amdgcn_readlane(__builtin_bit_cast(int, v), lane));
}

template<int CTRL>
__device__ __forceinline__ float dpp_fmax(float m)
{
    int sh = __builtin_amdgcn_update_dpp(0, __builtin_bit_cast(int, m), CTRL, 0xf, 0xf, true);
    return fmaxf(m, __builtin_bit_cast(float, sh));
}

// wave-wide max of non-negative values; valid in lane 63. Pure VALU (DPP).
__device__ __forceinline__ float wave_max_nn(float v)
{
    v = dpp_fmax<0x111>(v);   // row_shr:1
    v = dpp_fmax<0x112>(v);   // row_shr:2
    v = dpp_fmax<0x114>(v);   // row_shr:4
    v = dpp_fmax<0x118>(v);   // row_shr:8  -> lane 15/31/47/63 = row max
    v = dpp_fmax<0x142>(v);   // row_bcast:15 -> lane 31/63 = half max
    v = dpp_fmax<0x143>(v);   // row_bcast:31 -> lane 63 = wave max
    return v;
}

// Fused normalize + gram. Block i computes G row i; every thread j computes
// its own column norm (fp32, squares rounded individually, sequential sum
// over c ascending — op-for-op the old k_normalize), norms shared via LDS.
// Dn column i written by block i (values = D/nrm, identical rounding).
// G[i][j] = fmaf chain over c ascending of (D[c][i]/nrm_i)*(D[c][j]/nrm_j):
// each per-element division rounds exactly like the Dn store, so G is
// bit-identical to the old k_normalize->k_gram pipeline.
// Replaces the single-block k_normalize (a serial ~2x64-deep latency chain
// on one CU) with fully parallel work; drops one launch.
__global__ void k_ng(const float* __restrict__ D, float* __restrict__ Dn,
                     float* __restrict__ G,
                     double* __restrict__ loss_acc, unsigned int* __restrict__ ctr)
{
#pragma clang fp contract(off)
    __shared__ float nrmS[NEMB];
    __shared__ float coli[DIM];
    int i = blockIdx.x, j = threadIdx.x;
    if (i == 0 && j == 0) { loss_acc[0] = 0.0; ctr[0] = 0u; }
    float ss = 0.0f;
    for (int c = 0; c < DIM; c++) {
        float v = D[c * NEMB + j];
        float sq = v * v;
        ss = ss + sq;
    }
    float nrm = fmaxf(sqrtf(ss), 1e-10f);
    nrmS[j] = nrm;
    __syncthreads();
    if (j < DIM) {
        float dni = D[j * NEMB + i] / nrmS[i];
        coli[j] = dni;
        Dn[j * NEMB + i] = dni;         // block i owns Dn column i
    }
    __syncthreads();
    float s = 0.0f;
#pragma unroll 8
    for (int c = 0; c < DIM; c++) {
        float dnj = D[c * NEMB + j] / nrm;     // rounds identically to Dn[c][j]
        s = fmaf(coli[c], dnj, s);
    }
    G[i * NEMB + j] = s;
}

// mu-law quantize+decode, all fp32, numpy op-for-op (no fusion)
__device__ __forceinline__ float quant_decode(float coeff)
{
#pragma clang fp contract(off)
    float c = fminf(fmaxf(coeff, -3.0f), 3.0f) / 3.0f;
    float ac = fabsf(c);
    float sgn = (c > 0.0f) ? 1.0f : ((c < 0.0f) ? -1.0f : 0.0f);
    float l = log1pf(ac * 50.0f);
    float enc = (sgn * l) * INV_MU_F;
    float scaled = (enc + 1.0f) * 7.5f;
    int bin = (int)rintf(scaled);              // round-half-even == np.round
    bin = bin < 0 ? 0 : (bin > 15 ? 15 : bin);
    float t = (float)bin * TWO15_F;
    float zv = t - 1.0f;
    float az = fabsf(zv);
    float sz = (zv > 0.0f) ? 1.0f : ((zv < 0.0f) ? -1.0f : 0.0f);
    float e = expm1f(az / INV_MU_F);
    return (sz * (e / 50.0f)) * 3.0f;
}

// TWO signals' OMP (K=4) per call: argmax/residual distributed over all
// 64 lanes per signal (4 atoms/lane), wave-uniform Cholesky + triangular
// solves run ONCE on half-selected operands: lanes 0-31 compute signal A's
// recurrence, lanes 32-63 signal B's. Bit-identical per-signal arithmetic.
__device__ __forceinline__ void omp_pair(const f2* hbA_in, const f2* hbB_in,
                                         int lane, int hi,
                                         const float* __restrict__ G,
                                         float* __restrict__ xsv,
                                         int* __restrict__ qi, int sA)
{
#pragma clang fp contract(off)
    f2 hbsiA[2] = {hbA_in[0], hbA_in[1]};
    f2 hbsiB[2] = {hbB_in[0], hbB_in[1]};
    f2 hA[2] = {hbsiA[0], hbsiA[1]};
    f2 hB[2] = {hbsiB[0], hbsiB[1]};
    f2 GrA[3][2], GrB[3][2];
    float Lm[4][4];
    int IvA[4], IvB[4];
    float y[4], xs[4];
    int m4A = 0, m4B = 0;
#pragma unroll
    for (int kk = 0; kk < 4; kk++) {
        // ---- per-lane best of own 4 atoms, both signals (independent ILP) ----
        float bvA = -1.0f, bvB = -1.0f;
        int bjA = 0, bjB = 0;
#pragma unroll
        for (int j = 0; j < 4; j++) {
            float vA_ = (m4A & (1 << j)) ? 0.0f : fabsf(hA[j >> 1][j & 1]);
            if (vA_ > bvA) { bvA = vA_; bjA = j; }
            float vB_ = (m4B & (1 << j)) ? 0.0f : fabsf(hB[j >> 1][j & 1]);
            if (vB_ > bvB) { bvB = vB_; bjB = j; }
        }
        // ---- wave max via DPP (value only), two independent chains ----
        float mA = wave_max_nn(bvA);
        float mB = wave_max_nn(bvB);
        float vmaxA = rdlane_f(mA, 63);
        float vmaxB = rdlane_f(mB, 63);
        // ---- first lane holding the max = numpy first-index tie-break ----
        unsigned long long ballA = __ballot(bvA == vmaxA);
        unsigned long long ballB = __ballot(bvB == vmaxB);
        int ownerA = __ffsll((long long)ballA) - 1;
        int ownerB = __ffsll((long long)ballB) - 1;
        int bjAo = __builtin_amdgcn_readlane(bjA, ownerA);
        int bjBo = __builtin_amdgcn_readlane(bjB, ownerB);
        int idxA = 4 * ownerA + bjAo;
        int idxB = 4 * ownerB + bjBo;
        m4A |= (lane == ownerA) ? (1 << bjAo) : 0;
        m4B |= (lane == ownerB) ? (1 << bjBo) : 0;
        IvA[kk] = idxA; IvB[kk] = idxB;
        // ---- original h_bar value at selected atom ----
        float tvA = hbsiA[0][0];
        tvA = (bjA == 1) ? hbsiA[0][1] : tvA;
        tvA = (bjA == 2) ? hbsiA[1][0] : tvA;
        tvA = (bjA == 3) ? hbsiA[1][1] : tvA;
        float tvB = hbsiB[0][0];
        tvB = (bjB == 1) ? hbsiB[0][1] : tvB;
        tvB = (bjB == 2) ? hbsiB[1][0] : tvB;
        tvB = (bjB == 3) ? hbsiB[1][1] : tvB;
        float hselA = rdlane_f(tvA, ownerA);
        float hselB = rdlane_f(tvB, ownerB);
        float hsel = hi ? hselB : hselA;
        // ---- cache G rows for this atom (float4/lane, coalesced, L2-hot) ----
        if (kk < 3) {
            const float4 ga = *(const float4*)(G + ((size_t)idxA << 8) + 4 * lane);
            const float4 gb = *(const float4*)(G + ((size_t)idxB << 8) + 4 * lane);
            GrA[kk][0].x = ga.x; GrA[kk][0].y = ga.y;
            GrA[kk][1].x = ga.z; GrA[kk][1].y = ga.w;
            GrB[kk][0].x = gb.x; GrB[kk][0].y = gb.y;
            GrB[kk][1].x = gb.z; GrB[kk][1].y = gb.w;
        }
        // ---- Cholesky row update (halves: A on lanes 0-31, B on 32-63) ----
        if (kk > 0) {
            float Gs[3], w[3];
#pragma unroll
            for (int j = 0; j < 3; j++)
                if (j < kk) {
                    // G[Iv[j]][idx] == element bj_o of cached row j at lane owner
                    float eA = GrA[j][0][0];
                    eA = (bjAo == 1) ? GrA[j][0][1] : eA;
                    eA = (bjAo == 2) ? GrA[j][1][0] : eA;
                    eA = (bjAo == 3) ? GrA[j][1][1] : eA;
                    float eB = GrB[j][0][0];
                    eB = (bjBo == 1) ? GrB[j][0][1] : eB;
                    eB = (bjBo == 2) ? GrB[j][1][0] : eB;
                    eB = (bjBo == 3) ? GrB[j][1][1] : eB;
                    float gA = rdlane_f(eA, ownerA);
                    float gB = rdlane_f(eB, ownerB);
                    Gs[j] = hi ? gB : gA;
                }
#pragma unroll
            for (int r = 0; r < 3; r++) {
                if (r < kk) {
                    float acc = 0.0f;
#pragma unroll
                    for (int cc = 0; cc < 3; cc++)
                        if (cc < r) { float p = Lm[r][cc] * w[cc]; acc = acc + p; }
                    float t2 = Gs[r] - acc;
                    w[r] = (r == 0) ? t2 : t2 / Lm[r][r];   // L[0][0]==1: exact
                }
            }
            float ssum = 0.0f;
#pragma unroll
            for (int j = 0; j < 3; j++)
                if (j < kk) { float p = w[j] * w[j]; ssum = ssum + p; }
            float om = 1.0f - ssum;
            float wc = sqrtf(fmaxf(om, 1e-12f));
#pragma unroll
            for (int cc = 0; cc < 3; cc++)
                if (cc < kk) Lm[kk][cc] = w[cc];
            Lm[kk][kk] = wc;
        } else {
            Lm[0][0] = 1.0f;
        }
        // ---- forward solve, incremental: only row kk is new ----
        {
            float acc = 0.0f;
#pragma unroll
            for (int cc = 0; cc < 3; cc++)
                if (cc < kk) { float p = Lm[kk][cc] * y[cc]; acc = acc + p; }
            float t2 = hsel - acc;
            y[kk] = (kk == 0) ? t2 : t2 / Lm[kk][kk];
        }
        // ---- backward solve L^T x = y (full, sum ascending c>r) ----
#pragma unroll
        for (int r = 3; r >= 0; r--) {
            if (r <= kk) {
                float acc = 0.0f;
#pragma unroll
                for (int cc = 0; cc < 4; cc++)
                    if (cc > r && cc <= kk) { float p = Lm[cc][r] * xs[cc]; acc = acc + p; }
                float t2 = y[r] - acc;
                xs[r] = (r == 0) ? t2 : t2 / Lm[r][r];      // L[0][0]==1: exact
            }
        }
        // ---- residual: h = h_bar - einsum(x, G[I]) (mul+add, k ascending) ----
        if (kk < 3) {
            float xsA[4], xsB[4];
#pragma unroll
            for (int j = 0; j < 4; j++)
                if (j <= kk) {
                    xsA[j] = rdlane_f(xs[j], 0);
                    xsB[j] = rdlane_f(xs[j], 32);
                }
#pragma unroll
            for (int jp = 0; jp < 2; jp++) {
                f2 bsA = {0.0f, 0.0f};
                f2 bsB = {0.0f, 0.0f};
#pragma unroll
                for (int jj = 0; jj < 3; jj++)
                    if (jj <= kk) {
                        f2 xa = {xsA[jj], xsA[jj]};
                        f2 xb = {xsB[jj], xsB[jj]};
                        f2 pA = xa * GrA[jj][jp];
                        bsA = bsA + pA;
                        f2 pB = xb * GrB[jj][jp];
                        bsB = bsB + pB;
                    }
                hA[jp] = hbsiA[jp] - bsA;
                hB[jp] = hbsiB[jp] - bsB;
            }
        }
    }
    // lane 0 writes signal A, lane 32 writes signal B
    if ((lane & 31) == 0) {
        int s = sA + hi;
#pragma unroll
        for (int j = 0; j < 4; j++) {
            xsv[j * SIGS + s] = xs[j];   // raw coeff; quantized later in parallel
            qi[j * SIGS + s] = hi ? IvB[j] : IvA[j];
        }
    }
}

// __launch_bounds__(512, 6): 6 waves/EU -> 3 blocks/CU (k = 6*4/8).
// VGPR cap ~84 leaves the natural 64-VGPR allocation untouched (round-4
// lesson: (512,8)'s 64-cap forced 32 VGPR + full spill, FETCH 37->179MB,
// WRITE 78->404MB, dur +32%). 3 blocks/CU = +50% TLP over round-1's 2,
// with zero codegen pressure. LDS 37KB*3 = 111KB <= 160KB.
__launch_bounds__(THREADS, 6)
__global__ void k_omp(const float* __restrict__ z,
                      const float* __restrict__ Dn_g,
                      const float* __restrict__ G,
                      double* __restrict__ loss_acc,
                      unsigned int* __restrict__ ctr,
                      float* __restrict__ zq,
                      float* __restrict__ loss_out)
{
    extern __shared__ char smem[];
    float* sig = (float*)(smem + LB_SIG);
    float* xsv = (float*)(smem + LB_XS);
    int* qi = (int*)(smem + LB_QI);
    double* red = (double*)(smem + LB_RED);

    int tid = threadIdx.x;
    int lane = tid & 63;
    int hi = lane >> 5;
    int wid = tid >> 6;

    long sbase = (long)blockIdx.x * SIGS;   // 128 consecutive pixels, one batch b
    int b = (int)(sbase >> 12);
    int pl0 = (int)(sbase & 4095);
    const float* zb = z + ((size_t)b << 18) + pl0;
    // stage z_e -> sig[c][w], coalesced along w
    {
        int w = tid & (SIGS - 1);
        int g = tid >> 7;
#pragma unroll
        for (int i = 0; i < 16; i++) {
            int c = g * 16 + i;
            sig[c * SIGS + w] = zb[(size_t)c * 4096 + w];
        }
    }
    __syncthreads();

    // each wave: 16 signals in 2 groups of 8; h_bar = X^T Dn, fp32 fused-FMA
    // sequential over c ascending, packed as float2 -> v_pk_fma_f32
    // (elementwise-identical fma chains). Dn read from global (L1/L2-hot).
    for (int g2 = 0; g2 < 2; g2++) {
        int s0 = wid * 16 + g2 * 8;
        f2 hb[8][2];
#pragma unroll
        for (int a = 0; a < 8; a++) {
            hb[a][0] = (f2){0.0f, 0.0f};
            hb[a][1] = (f2){0.0f, 0.0f};
        }
#pragma unroll 8
        for (int c = 0; c < DIM; c++) {
            float4 sva = *(const float4*)(sig + c * SIGS + s0);
            float4 svb = *(const float4*)(sig + c * SIGS + s0 + 4);
            float s8[8] = {sva.x, sva.y, sva.z, sva.w, svb.x, svb.y, svb.z, svb.w};
            float4 dv = *(const float4*)(Dn_g + c * NEMB + 4 * lane);
            f2 d0; d0.x = dv.x; d0.y = dv.y;
            f2 d1; d1.x = dv.z; d1.y = dv.w;
#pragma unroll
            for (int a = 0; a < 8; a++) {
                f2 sa = {s8[a], s8[a]};
                hb[a][0] = __builtin_elementwise_fma(sa, d0, hb[a][0]);
                hb[a][1] = __builtin_elementwise_fma(sa, d1, hb[a][1]);
            }
        }
#pragma unroll
        for (int p = 0; p < 4; p++)
            omp_pair(hb[2 * p], hb[2 * p + 1], lane, hi, G, xsv, qi, s0 + 2 * p);
    }
    __syncthreads();

    // thread-parallel mu-law quantize of all 512 coeffs
    {
        int jq = tid >> 7;
        int wq = tid & (SIGS - 1);
        xsv[jq * SIGS + wq] = quant_decode(xsv[jq * SIGS + wq]);
    }
    __syncthreads();

    // store phase: recon (einsum order: mul+add, k ascending, no fma),
    // z_q = z_e + (recon - z_e), loss accumulated in f64
    double lsum = 0.0;
    float* zqb = zq + ((size_t)b << 18) + pl0;
    {
#pragma clang fp contract(off)
        int w = tid & (SIGS - 1);
        int g = tid >> 7;
        float q0 = xsv[0 * SIGS + w], q1 = xsv[1 * SIGS + w];
        float q2 = xsv[2 * SIGS + w], q3 = xsv[3 * SIGS + w];
        int i0 = qi[0 * SIGS + w], i1 = qi[1 * SIGS + w];
        int i2 = qi[2 * SIGS + w], i3 = qi[3 * SIGS + w];
#pragma unroll
        for (int ci = 0; ci < 16; ci++) {
            int c = g * 16 + ci;
            const float* dr = Dn_g + c * NEMB;
            float p0 = q0 * dr[i0];
            float p1 = q1 * dr[i1];
            float p2 = q2 * dr[i2];
            float p3 = q3 * dr[i3];
            float r = p0 + p1;
            r = r + p2;
            r = r + p3;
            float zev = sig[c * SIGS + w];
            float d = r - zev;
            float zqv = zev + d;           // z_q = z_e + (recon - z_e)
            lsum += (double)d * (double)d;
            zqb[(size_t)c * 4096 + w] = zqv;
        }
    }
#pragma unroll
    for (int off = 32; off > 0; off >>= 1) lsum += __shfl_xor(lsum, off);
    if (lane == 0) red[wid] = lsum;
    __syncthreads();
    if (tid == 0) {
        double t = 0.0;
#pragma unroll
        for (int i = 0; i < 8; i++) t += red[i];
        atomicAdd(loss_acc, t);
        __threadfence();
        unsigned int done = atomicAdd(ctr, 1u);
        if (done == GRID - 1) {
            double m = atomicAdd(loss_acc, 0.0) / 8388608.0;
            loss_out[0] = (float)(m + 0.25 * m);
        }
    }
}

extern "C" void kernel_launch(void* const* d_in, const int* in_sizes, int n_in,
                              void* d_out, int out_size, void* d_ws, size_t ws_size,
                              hipStream_t stream)
{
    const float* z = (const float*)d_in[0];
    const float* D = (const float*)d_in[1];
    float* out = (float*)d_out;
    char* ws = (char*)d_ws;
    double* loss_acc = (double*)ws;              // 8 B
    unsigned int* ctr = (unsigned int*)(ws + 8); // 4 B
    float* Dn = (float*)(ws + 256);              // 64x256 f32
    float* G = (float*)(ws + 256 + 65536);       // 256x256 f32

    k_ng<<<NEMB, NEMB, 0, stream>>>(D, Dn, G, loss_acc, ctr);
    hipFuncSetAttribute(reinterpret_cast<const void*>(k_omp),
                        hipFuncAttributeMaxDynamicSharedMemorySize, LDS_BYTES);
    k_omp<<<GRID, THREADS, LDS_BYTES, stream>>>(z, Dn, G, loss_acc, ctr, out, out + 8388608);
    (void)in_sizes; (void)n_in; (void)out_size; (void)ws_size;
}

// Round 6
// 309.285 us; speedup vs baseline: 2.0842x; 1.0088x over previous
//
#include <hip/hip_runtime.h>
#include <math.h>

#define NEMB 256
#define DIM 64
#define SIGS_B 64                 // signals per block (was 128)
#define THREADS 256               // 4 waves per block
#define NSIG 131072
#define GRID (NSIG / SIGS_B)      // 2048 = 8 blocks/CU x 256 CU, zero tail

#define LOG1P50 3.9318256327243257        // np.log1p(50.0), f64
#define INV_MU_F ((float)(1.0 / LOG1P50)) // fp32-rounded scalar, as numpy uses
#define TWO15_F ((float)(2.0 / 15.0))

// dynamic LDS layout (byte offsets) — Dn NOT staged (L2-hot from global)
// 18.5 KB/block -> 8 blocks/CU by LDS (148 KB); 64 VGPR -> 8 waves/SIMD.
// Both limits land at 8 blocks/CU: 2x round-1's TLP with identical codegen.
#define LB_SIG   0          // 16384 B : sig f32 [c][w]  (64 x 64)
#define LB_XS    16384      // 1024 B  : raw coeffs f32 [4][SIGS_B]
#define LB_QI    17408      // 1024 B  : qi i32 [4][SIGS_B]
#define LB_RED   18432      // 32 B    : per-wave loss partials (f64)
#define LDS_BYTES 18464

typedef float f2 __attribute__((ext_vector_type(2)));

__device__ __forceinline__ float rdlane_f(float v, int lane)
{
    return __builtin_bit_cast(float, __builtin_amdgcn_readlane(__builtin_bit_cast(int, v), lane));
}

template<int CTRL>
__device__ __forceinline__ float dpp_fmax(float m)
{
    int sh = __builtin_amdgcn_update_dpp(0, __builtin_bit_cast(int, m), CTRL, 0xf, 0xf, true);
    return fmaxf(m, __builtin_bit_cast(float, sh));
}

// wave-wide max of non-negative values; valid in lane 63. Pure VALU (DPP).
__device__ __forceinline__ float wave_max_nn(float v)
{
    v = dpp_fmax<0x111>(v);   // row_shr:1
    v = dpp_fmax<0x112>(v);   // row_shr:2
    v = dpp_fmax<0x114>(v);   // row_shr:4
    v = dpp_fmax<0x118>(v);   // row_shr:8  -> lane 15/31/47/63 = row max
    v = dpp_fmax<0x142>(v);   // row_bcast:15 -> lane 31/63 = half max
    v = dpp_fmax<0x143>(v);   // row_bcast:31 -> lane 63 = wave max
    return v;
}

// Fused normalize + gram (neutral vs separate kernels, kept: one launch less).
// Block i computes G row i; every thread j computes its own column norm
// (fp32, squares rounded individually, sequential sum over c ascending),
// norms shared via LDS. G bit-identical to normalize->gram pipeline.
__global__ void k_ng(const float* __restrict__ D, float* __restrict__ Dn,
                     float* __restrict__ G,
                     double* __restrict__ loss_acc, unsigned int* __restrict__ ctr)
{
#pragma clang fp contract(off)
    __shared__ float nrmS[NEMB];
    __shared__ float coli[DIM];
    int i = blockIdx.x, j = threadIdx.x;
    if (i == 0 && j == 0) { loss_acc[0] = 0.0; ctr[0] = 0u; }
    float ss = 0.0f;
    for (int c = 0; c < DIM; c++) {
        float v = D[c * NEMB + j];
        float sq = v * v;
        ss = ss + sq;
    }
    float nrm = fmaxf(sqrtf(ss), 1e-10f);
    nrmS[j] = nrm;
    __syncthreads();
    if (j < DIM) {
        float dni = D[j * NEMB + i] / nrmS[i];
        coli[j] = dni;
        Dn[j * NEMB + i] = dni;         // block i owns Dn column i
    }
    __syncthreads();
    float s = 0.0f;
#pragma unroll 8
    for (int c = 0; c < DIM; c++) {
        float dnj = D[c * NEMB + j] / nrm;     // rounds identically to Dn[c][j]
        s = fmaf(coli[c], dnj, s);
    }
    G[i * NEMB + j] = s;
}

// mu-law quantize+decode, all fp32, numpy op-for-op (no fusion)
__device__ __forceinline__ float quant_decode(float coeff)
{
#pragma clang fp contract(off)
    float c = fminf(fmaxf(coeff, -3.0f), 3.0f) / 3.0f;
    float ac = fabsf(c);
    float sgn = (c > 0.0f) ? 1.0f : ((c < 0.0f) ? -1.0f : 0.0f);
    float l = log1pf(ac * 50.0f);
    float enc = (sgn * l) * INV_MU_F;
    float scaled = (enc + 1.0f) * 7.5f;
    int bin = (int)rintf(scaled);              // round-half-even == np.round
    bin = bin < 0 ? 0 : (bin > 15 ? 15 : bin);
    float t = (float)bin * TWO15_F;
    float zv = t - 1.0f;
    float az = fabsf(zv);
    float sz = (zv > 0.0f) ? 1.0f : ((zv < 0.0f) ? -1.0f : 0.0f);
    float e = expm1f(az / INV_MU_F);
    return (sz * (e / 50.0f)) * 3.0f;
}

// TWO signals' OMP (K=4) per call: argmax/residual distributed over all
// 64 lanes per signal (4 atoms/lane), wave-uniform Cholesky + triangular
// solves run ONCE on half-selected operands: lanes 0-31 compute signal A's
// recurrence, lanes 32-63 signal B's. Bit-identical per-signal arithmetic.
__device__ __forceinline__ void omp_pair(const f2* hbA_in, const f2* hbB_in,
                                         int lane, int hi,
                                         const float* __restrict__ G,
                                         float* __restrict__ xsv,
                                         int* __restrict__ qi, int sA)
{
#pragma clang fp contract(off)
    f2 hbsiA[2] = {hbA_in[0], hbA_in[1]};
    f2 hbsiB[2] = {hbB_in[0], hbB_in[1]};
    f2 hA[2] = {hbsiA[0], hbsiA[1]};
    f2 hB[2] = {hbsiB[0], hbsiB[1]};
    f2 GrA[3][2], GrB[3][2];
    float Lm[4][4];
    int IvA[4], IvB[4];
    float y[4], xs[4];
    int m4A = 0, m4B = 0;
#pragma unroll
    for (int kk = 0; kk < 4; kk++) {
        // ---- per-lane best of own 4 atoms, both signals (independent ILP) ----
        float bvA = -1.0f, bvB = -1.0f;
        int bjA = 0, bjB = 0;
#pragma unroll
        for (int j = 0; j < 4; j++) {
            float vA_ = (m4A & (1 << j)) ? 0.0f : fabsf(hA[j >> 1][j & 1]);
            if (vA_ > bvA) { bvA = vA_; bjA = j; }
            float vB_ = (m4B & (1 << j)) ? 0.0f : fabsf(hB[j >> 1][j & 1]);
            if (vB_ > bvB) { bvB = vB_; bjB = j; }
        }
        // ---- wave max via DPP (value only), two independent chains ----
        float mA = wave_max_nn(bvA);
        float mB = wave_max_nn(bvB);
        float vmaxA = rdlane_f(mA, 63);
        float vmaxB = rdlane_f(mB, 63);
        // ---- first lane holding the max = numpy first-index tie-break ----
        unsigned long long ballA = __ballot(bvA == vmaxA);
        unsigned long long ballB = __ballot(bvB == vmaxB);
        int ownerA = __ffsll((long long)ballA) - 1;
        int ownerB = __ffsll((long long)ballB) - 1;
        int bjAo = __builtin_amdgcn_readlane(bjA, ownerA);
        int bjBo = __builtin_amdgcn_readlane(bjB, ownerB);
        int idxA = 4 * ownerA + bjAo;
        int idxB = 4 * ownerB + bjBo;
        m4A |= (lane == ownerA) ? (1 << bjAo) : 0;
        m4B |= (lane == ownerB) ? (1 << bjBo) : 0;
        IvA[kk] = idxA; IvB[kk] = idxB;
        // ---- original h_bar value at selected atom ----
        float tvA = hbsiA[0][0];
        tvA = (bjA == 1) ? hbsiA[0][1] : tvA;
        tvA = (bjA == 2) ? hbsiA[1][0] : tvA;
        tvA = (bjA == 3) ? hbsiA[1][1] : tvA;
        float tvB = hbsiB[0][0];
        tvB = (bjB == 1) ? hbsiB[0][1] : tvB;
        tvB = (bjB == 2) ? hbsiB[1][0] : tvB;
        tvB = (bjB == 3) ? hbsiB[1][1] : tvB;
        float hselA = rdlane_f(tvA, ownerA);
        float hselB = rdlane_f(tvB, ownerB);
        float hsel = hi ? hselB : hselA;
        // ---- cache G rows for this atom (float4/lane, coalesced, L2-hot) ----
        if (kk < 3) {
            const float4 ga = *(const float4*)(G + ((size_t)idxA << 8) + 4 * lane);
            const float4 gb = *(const float4*)(G + ((size_t)idxB << 8) + 4 * lane);
            GrA[kk][0].x = ga.x; GrA[kk][0].y = ga.y;
            GrA[kk][1].x = ga.z; GrA[kk][1].y = ga.w;
            GrB[kk][0].x = gb.x; GrB[kk][0].y = gb.y;
            GrB[kk][1].x = gb.z; GrB[kk][1].y = gb.w;
        }
        // ---- Cholesky row update (halves: A on lanes 0-31, B on 32-63) ----
        if (kk > 0) {
            float Gs[3], w[3];
#pragma unroll
            for (int j = 0; j < 3; j++)
                if (j < kk) {
                    // G[Iv[j]][idx] == element bj_o of cached row j at lane owner
                    float eA = GrA[j][0][0];
                    eA = (bjAo == 1) ? GrA[j][0][1] : eA;
                    eA = (bjAo == 2) ? GrA[j][1][0] : eA;
                    eA = (bjAo == 3) ? GrA[j][1][1] : eA;
                    float eB = GrB[j][0][0];
                    eB = (bjBo == 1) ? GrB[j][0][1] : eB;
                    eB = (bjBo == 2) ? GrB[j][1][0] : eB;
                    eB = (bjBo == 3) ? GrB[j][1][1] : eB;
                    float gA = rdlane_f(eA, ownerA);
                    float gB = rdlane_f(eB, ownerB);
                    Gs[j] = hi ? gB : gA;
                }
#pragma unroll
            for (int r = 0; r < 3; r++) {
                if (r < kk) {
                    float acc = 0.0f;
#pragma unroll
                    for (int cc = 0; cc < 3; cc++)
                        if (cc < r) { float p = Lm[r][cc] * w[cc]; acc = acc + p; }
                    float t2 = Gs[r] - acc;
                    w[r] = (r == 0) ? t2 : t2 / Lm[r][r];   // L[0][0]==1: exact
                }
            }
            float ssum = 0.0f;
#pragma unroll
            for (int j = 0; j < 3; j++)
                if (j < kk) { float p = w[j] * w[j]; ssum = ssum + p; }
            float om = 1.0f - ssum;
            float wc = sqrtf(fmaxf(om, 1e-12f));
#pragma unroll
            for (int cc = 0; cc < 3; cc++)
                if (cc < kk) Lm[kk][cc] = w[cc];
            Lm[kk][kk] = wc;
        } else {
            Lm[0][0] = 1.0f;
        }
        // ---- forward solve, incremental: only row kk is new ----
        {
            float acc = 0.0f;
#pragma unroll
            for (int cc = 0; cc < 3; cc++)
                if (cc < kk) { float p = Lm[kk][cc] * y[cc]; acc = acc + p; }
            float t2 = hsel - acc;
            y[kk] = (kk == 0) ? t2 : t2 / Lm[kk][kk];
        }
        // ---- backward solve L^T x = y (full, sum ascending c>r) ----
#pragma unroll
        for (int r = 3; r >= 0; r--) {
            if (r <= kk) {
                float acc = 0.0f;
#pragma unroll
                for (int cc = 0; cc < 4; cc++)
                    if (cc > r && cc <= kk) { float p = Lm[cc][r] * xs[cc]; acc = acc + p; }
                float t2 = y[r] - acc;
                xs[r] = (r == 0) ? t2 : t2 / Lm[r][r];      // L[0][0]==1: exact
            }
        }
        // ---- residual: h = h_bar - einsum(x, G[I]) (mul+add, k ascending) ----
        if (kk < 3) {
            float xsA[4], xsB[4];
#pragma unroll
            for (int j = 0; j < 4; j++)
                if (j <= kk) {
                    xsA[j] = rdlane_f(xs[j], 0);
                    xsB[j] = rdlane_f(xs[j], 32);
                }
#pragma unroll
            for (int jp = 0; jp < 2; jp++) {
                f2 bsA = {0.0f, 0.0f};
                f2 bsB = {0.0f, 0.0f};
#pragma unroll
                for (int jj = 0; jj < 3; jj++)
                    if (jj <= kk) {
                        f2 xa = {xsA[jj], xsA[jj]};
                        f2 xb = {xsB[jj], xsB[jj]};
                        f2 pA = xa * GrA[jj][jp];
                        bsA = bsA + pA;
                        f2 pB = xb * GrB[jj][jp];
                        bsB = bsB + pB;
                    }
                hA[jp] = hbsiA[jp] - bsA;
                hB[jp] = hbsiB[jp] - bsB;
            }
        }
    }
    // lane 0 writes signal A, lane 32 writes signal B
    if ((lane & 31) == 0) {
        int s = sA + hi;
#pragma unroll
        for (int j = 0; j < 4; j++) {
            xsv[j * SIGS_B + s] = xs[j];   // raw coeff; quantized later in parallel
            qi[j * SIGS_B + s] = hi ? IvB[j] : IvA[j];
        }
    }
}

// __launch_bounds__(256, 4): the PROVEN clean allocator point (cap 128, same
// as round-1's (512,4) which picked 64 VGPR spill-free). TLP now comes from
// block granularity: 18.5 KB LDS x 8 blocks = 148 KB and 64 VGPR x 8 waves
// both allow 8 blocks/CU = 8 waves/SIMD — 2x round-1 — without touching the
// VGPR cap (round-4/5 lesson: caps <128 trigger 32/40-VGPR spill codegen).
__launch_bounds__(THREADS, 4)
__global__ void k_omp(const float* __restrict__ z,
                      const float* __restrict__ Dn_g,
                      const float* __restrict__ G,
                      double* __restrict__ loss_acc,
                      unsigned int* __restrict__ ctr,
                      float* __restrict__ zq,
                      float* __restrict__ loss_out)
{
    extern __shared__ char smem[];
    float* sig = (float*)(smem + LB_SIG);
    float* xsv = (float*)(smem + LB_XS);
    int* qi = (int*)(smem + LB_QI);
    double* red = (double*)(smem + LB_RED);

    int tid = threadIdx.x;
    int lane = tid & 63;
    int hi = lane >> 5;
    int wid = tid >> 6;          // 0..3

    long sbase = (long)blockIdx.x * SIGS_B;  // 64 consecutive pixels, one batch b
    int b = (int)(sbase >> 12);
    int pl0 = (int)(sbase & 4095);
    const float* zb = z + ((size_t)b << 18) + pl0;
    // stage z_e -> sig[c][w], coalesced along w (256B per c-row per block)
    {
        int w = tid & (SIGS_B - 1);
        int g = tid >> 6;
#pragma unroll
        for (int i = 0; i < 16; i++) {
            int c = g * 16 + i;
            sig[c * SIGS_B + w] = zb[(size_t)c * 4096 + w];
        }
    }
    __syncthreads();

    // each wave: 16 signals in 2 groups of 8; h_bar = X^T Dn, fp32 fused-FMA
    // sequential over c ascending, packed as float2 -> v_pk_fma_f32
    // (elementwise-identical fma chains). Dn read from global (L1/L2-hot).
    for (int g2 = 0; g2 < 2; g2++) {
        int s0 = wid * 16 + g2 * 8;
        f2 hb[8][2];
#pragma unroll
        for (int a = 0; a < 8; a++) {
            hb[a][0] = (f2){0.0f, 0.0f};
            hb[a][1] = (f2){0.0f, 0.0f};
        }
#pragma unroll 8
        for (int c = 0; c < DIM; c++) {
            float4 sva = *(const float4*)(sig + c * SIGS_B + s0);
            float4 svb = *(const float4*)(sig + c * SIGS_B + s0 + 4);
            float s8[8] = {sva.x, sva.y, sva.z, sva.w, svb.x, svb.y, svb.z, svb.w};
            float4 dv = *(const float4*)(Dn_g + c * NEMB + 4 * lane);
            f2 d0; d0.x = dv.x; d0.y = dv.y;
            f2 d1; d1.x = dv.z; d1.y = dv.w;
#pragma unroll
            for (int a = 0; a < 8; a++) {
                f2 sa = {s8[a], s8[a]};
                hb[a][0] = __builtin_elementwise_fma(sa, d0, hb[a][0]);
                hb[a][1] = __builtin_elementwise_fma(sa, d1, hb[a][1]);
            }
        }
#pragma unroll
        for (int p = 0; p < 4; p++)
            omp_pair(hb[2 * p], hb[2 * p + 1], lane, hi, G, xsv, qi, s0 + 2 * p);
    }
    __syncthreads();

    // thread-parallel mu-law quantize of all 256 coeffs (one per thread)
    {
        int jq = tid >> 6;
        int wq = tid & (SIGS_B - 1);
        xsv[jq * SIGS_B + wq] = quant_decode(xsv[jq * SIGS_B + wq]);
    }
    __syncthreads();

    // store phase: recon (einsum order: mul+add, k ascending, no fma),
    // z_q = z_e + (recon - z_e), loss accumulated in f64
    double lsum = 0.0;
    float* zqb = zq + ((size_t)b << 18) + pl0;
    {
#pragma clang fp contract(off)
        int w = tid & (SIGS_B - 1);
        int g = tid >> 6;
        float q0 = xsv[0 * SIGS_B + w], q1 = xsv[1 * SIGS_B + w];
        float q2 = xsv[2 * SIGS_B + w], q3 = xsv[3 * SIGS_B + w];
        int i0 = qi[0 * SIGS_B + w], i1 = qi[1 * SIGS_B + w];
        int i2 = qi[2 * SIGS_B + w], i3 = qi[3 * SIGS_B + w];
#pragma unroll
        for (int ci = 0; ci < 16; ci++) {
            int c = g * 16 + ci;
            const float* dr = Dn_g + c * NEMB;
            float p0 = q0 * dr[i0];
            float p1 = q1 * dr[i1];
            float p2 = q2 * dr[i2];
            float p3 = q3 * dr[i3];
            float r = p0 + p1;
            r = r + p2;
            r = r + p3;
            float zev = sig[c * SIGS_B + w];
            float d = r - zev;
            float zqv = zev + d;           // z_q = z_e + (recon - z_e)
            lsum += (double)d * (double)d;
            zqb[(size_t)c * 4096 + w] = zqv;
        }
    }
#pragma unroll
    for (int off = 32; off > 0; off >>= 1) lsum += __shfl_xor(lsum, off);
    if (lane == 0) red[wid] = lsum;
    __syncthreads();
    if (tid == 0) {
        double t = 0.0;
#pragma unroll
        for (int i = 0; i < 4; i++) t += red[i];
        atomicAdd(loss_acc, t);
        __threadfence();
        unsigned int done = atomicAdd(ctr, 1u);
        if (done == GRID - 1) {
            double m = atomicAdd(loss_acc, 0.0) / 8388608.0;
            loss_out[0] = (float)(m + 0.25 * m);
        }
    }
}

extern "C" void kernel_launch(void* const* d_in, const int* in_sizes, int n_in,
                              void* d_out, int out_size, void* d_ws, size_t ws_size,
                              hipStream_t stream)
{
    const float* z = (const float*)d_in[0];
    const float* D = (const float*)d_in[1];
    float* out = (float*)d_out;
    char* ws = (char*)d_ws;
    double* loss_acc = (double*)ws;              // 8 B
    unsigned int* ctr = (unsigned int*)(ws + 8); // 4 B
    float* Dn = (float*)(ws + 256);              // 64x256 f32
    float* G = (float*)(ws + 256 + 65536);       // 256x256 f32

    k_ng<<<NEMB, NEMB, 0, stream>>>(D, Dn, G, loss_acc, ctr);
    hipFuncSetAttribute(reinterpret_cast<const void*>(k_omp),
                        hipFuncAttributeMaxDynamicSharedMemorySize, LDS_BYTES);
    k_omp<<<GRID, THREADS, LDS_BYTES, stream>>>(z, Dn, G, loss_acc, ctr, out, out + 8388608);
    (void)in_sizes; (void)n_in; (void)out_size; (void)ws_size;
}

// Round 7
// 299.484 us; speedup vs baseline: 2.1524x; 1.0327x over previous
//
#include <hip/hip_runtime.h>
#include <math.h>

#define NEMB 256
#define DIM 64
#define SIGS_B 64                 // signals per block
#define THREADS 256               // 4 waves per block
#define NSIG 131072
#define GRID (NSIG / SIGS_B)      // 2048

#define LOG1P50 3.9318256327243257        // np.log1p(50.0), f64
#define INV_MU_F ((float)(1.0 / LOG1P50)) // fp32-rounded scalar, as numpy uses
#define TWO15_F ((float)(2.0 / 15.0))

// dynamic LDS layout (byte offsets) — Dn NOT staged (L2-hot from global)
#define LB_SIG   0          // 16384 B : sig f32 [c][w]  (64 x 64)
#define LB_XS    16384      // 1024 B  : raw coeffs f32 [4][SIGS_B]
#define LB_QI    17408      // 1024 B  : qi i32 [4][SIGS_B]
#define LB_RED   18432      // 32 B    : per-wave loss partials (f64)
#define LDS_BYTES 18464

typedef float f2 __attribute__((ext_vector_type(2)));

__device__ __forceinline__ float rdlane_f(float v, int lane)
{
    return __builtin_bit_cast(float, __builtin_amdgcn_readlane(__builtin_bit_cast(int, v), lane));
}

template<int CTRL>
__device__ __forceinline__ float dpp_fmax(float m)
{
    int sh = __builtin_amdgcn_update_dpp(0, __builtin_bit_cast(int, m), CTRL, 0xf, 0xf, true);
    return fmaxf(m, __builtin_bit_cast(float, sh));
}

// wave-wide max of non-negative values; valid in lane 63. Pure VALU (DPP).
__device__ __forceinline__ float wave_max_nn(float v)
{
    v = dpp_fmax<0x111>(v);   // row_shr:1
    v = dpp_fmax<0x112>(v);   // row_shr:2
    v = dpp_fmax<0x114>(v);   // row_shr:4
    v = dpp_fmax<0x118>(v);   // row_shr:8  -> lane 15/31/47/63 = row max
    v = dpp_fmax<0x142>(v);   // row_bcast:15 -> lane 31/63 = half max
    v = dpp_fmax<0x143>(v);   // row_bcast:31 -> lane 63 = wave max
    return v;
}

// Fused normalize + gram (+ DnT transpose for the store-phase vector gathers).
// Block i computes G row i; every thread j computes its own column norm
// (fp32, squares rounded individually, sequential sum over c ascending),
// norms shared via LDS. G bit-identical to normalize->gram pipeline.
// DnT[i][c] = Dn[c][i], the SAME dni value stored twice (bit-identical).
__global__ void k_ng(const float* __restrict__ D, float* __restrict__ Dn,
                     float* __restrict__ DnT, float* __restrict__ G,
                     double* __restrict__ loss_acc, unsigned int* __restrict__ ctr)
{
#pragma clang fp contract(off)
    __shared__ float nrmS[NEMB];
    __shared__ float coli[DIM];
    int i = blockIdx.x, j = threadIdx.x;
    if (i == 0 && j == 0) { loss_acc[0] = 0.0; ctr[0] = 0u; }
    float ss = 0.0f;
    for (int c = 0; c < DIM; c++) {
        float v = D[c * NEMB + j];
        float sq = v * v;
        ss = ss + sq;
    }
    float nrm = fmaxf(sqrtf(ss), 1e-10f);
    nrmS[j] = nrm;
    __syncthreads();
    if (j < DIM) {
        float dni = D[j * NEMB + i] / nrmS[i];
        coli[j] = dni;
        Dn[j * NEMB + i] = dni;         // block i owns Dn column i
        DnT[i * DIM + j] = dni;         // and DnT row i (same bits)
    }
    __syncthreads();
    float s = 0.0f;
#pragma unroll 8
    for (int c = 0; c < DIM; c++) {
        float dnj = D[c * NEMB + j] / nrm;     // rounds identically to Dn[c][j]
        s = fmaf(coli[c], dnj, s);
    }
    G[i * NEMB + j] = s;
}

// mu-law quantize+decode, all fp32, numpy op-for-op (no fusion)
__device__ __forceinline__ float quant_decode(float coeff)
{
#pragma clang fp contract(off)
    float c = fminf(fmaxf(coeff, -3.0f), 3.0f) / 3.0f;
    float ac = fabsf(c);
    float sgn = (c > 0.0f) ? 1.0f : ((c < 0.0f) ? -1.0f : 0.0f);
    float l = log1pf(ac * 50.0f);
    float enc = (sgn * l) * INV_MU_F;
    float scaled = (enc + 1.0f) * 7.5f;
    int bin = (int)rintf(scaled);              // round-half-even == np.round
    bin = bin < 0 ? 0 : (bin > 15 ? 15 : bin);
    float t = (float)bin * TWO15_F;
    float zv = t - 1.0f;
    float az = fabsf(zv);
    float sz = (zv > 0.0f) ? 1.0f : ((zv < 0.0f) ? -1.0f : 0.0f);
    float e = expm1f(az / INV_MU_F);
    return (sz * (e / 50.0f)) * 3.0f;
}

// FOUR signals' OMP (K=4) per call. Selection/residual stay distributed over
// all 64 lanes per signal (4 atoms/lane, unchanged layout); the wave-uniform
// Cholesky + triangular solves run ONCE on quarter-selected operands: lanes
// 16m..16m+15 compute signal m's recurrence. vs the 2-signal version this
// halves the serial div/sqrt chains per wave (32 -> 16).
//  - Gs = G[Iv[j]][idx] and the residual G-rows are direct loads (L1/L2-hot,
//    round-3-proven pattern) instead of cndmask/readlane extraction trees:
//    fewer issue slots; latency hidden under the solve stream.
//  - chol/solve scalar blocks lifted verbatim from the round-3 PASSING
//    kernel; selection machinery from the round-6 PASSING kernel.
//  - per-signal fp op sequence identical to all passing versions.
__device__ __forceinline__ void omp_quad(const f2 (*hbsi)[2], int lane, int qt,
                                         const float* __restrict__ G,
                                         float* __restrict__ xsv,
                                         int* __restrict__ qi, int s0)
{
#pragma clang fp contract(off)
    f2 h0[2] = {hbsi[0][0], hbsi[0][1]};
    f2 h1[2] = {hbsi[1][0], hbsi[1][1]};
    f2 h2[2] = {hbsi[2][0], hbsi[2][1]};
    f2 h3[2] = {hbsi[3][0], hbsi[3][1]};
    int m40 = 0, m41 = 0, m42 = 0, m43 = 0;
    int Iv0[4], Iv1[4], Iv2[4], Iv3[4];   // uniform (SGPR) support indices
    int Ivq[4];                            // own quarter's support indices
    float L10, L11, L20, L21, L22, L30, L31, L32, L33;
    float y0, y1, y2, y3;
    float x0 = 0.f, x1 = 0.f, x2 = 0.f, x3 = 0.f;
#pragma unroll
    for (int kk = 0; kk < 4; kk++) {
        // ---- per-lane best of own 4 atoms, 4 independent chains ----
        float bv0 = -1.f, bv1 = -1.f, bv2 = -1.f, bv3 = -1.f;
        int bj0 = 0, bj1 = 0, bj2 = 0, bj3 = 0;
#pragma unroll
        for (int j = 0; j < 4; j++) {
            float a0 = (m40 & (1 << j)) ? 0.f : fabsf(h0[j >> 1][j & 1]);
            if (a0 > bv0) { bv0 = a0; bj0 = j; }
            float a1 = (m41 & (1 << j)) ? 0.f : fabsf(h1[j >> 1][j & 1]);
            if (a1 > bv1) { bv1 = a1; bj1 = j; }
            float a2 = (m42 & (1 << j)) ? 0.f : fabsf(h2[j >> 1][j & 1]);
            if (a2 > bv2) { bv2 = a2; bj2 = j; }
            float a3 = (m43 & (1 << j)) ? 0.f : fabsf(h3[j >> 1][j & 1]);
            if (a3 > bv3) { bv3 = a3; bj3 = j; }
        }
        // ---- wave max (value only) x4, then first-lane tie-break ----
        float r0 = wave_max_nn(bv0);
        float r1 = wave_max_nn(bv1);
        float r2 = wave_max_nn(bv2);
        float r3 = wave_max_nn(bv3);
        float vm0 = rdlane_f(r0, 63), vm1 = rdlane_f(r1, 63);
        float vm2 = rdlane_f(r2, 63), vm3 = rdlane_f(r3, 63);
        unsigned long long bl0 = __ballot(bv0 == vm0);
        unsigned long long bl1 = __ballot(bv1 == vm1);
        unsigned long long bl2 = __ballot(bv2 == vm2);
        unsigned long long bl3 = __ballot(bv3 == vm3);
        int ow0 = __ffsll((long long)bl0) - 1;
        int ow1 = __ffsll((long long)bl1) - 1;
        int ow2 = __ffsll((long long)bl2) - 1;
        int ow3 = __ffsll((long long)bl3) - 1;
        int bo0 = __builtin_amdgcn_readlane(bj0, ow0);
        int bo1 = __builtin_amdgcn_readlane(bj1, ow1);
        int bo2 = __builtin_amdgcn_readlane(bj2, ow2);
        int bo3 = __builtin_amdgcn_readlane(bj3, ow3);
        int id0 = 4 * ow0 + bo0;           // uniform
        int id1 = 4 * ow1 + bo1;
        int id2 = 4 * ow2 + bo2;
        int id3 = 4 * ow3 + bo3;
        m40 |= (lane == ow0) ? (1 << bo0) : 0;
        m41 |= (lane == ow1) ? (1 << bo1) : 0;
        m42 |= (lane == ow2) ? (1 << bo2) : 0;
        m43 |= (lane == ow3) ? (1 << bo3) : 0;
        // ---- original h_bar at selected atom (local tree + owner readlane) ----
        float tv0 = hbsi[0][0][0];
        tv0 = (bj0 == 1) ? hbsi[0][0][1] : tv0;
        tv0 = (bj0 == 2) ? hbsi[0][1][0] : tv0;
        tv0 = (bj0 == 3) ? hbsi[0][1][1] : tv0;
        float tv1 = hbsi[1][0][0];
        tv1 = (bj1 == 1) ? hbsi[1][0][1] : tv1;
        tv1 = (bj1 == 2) ? hbsi[1][1][0] : tv1;
        tv1 = (bj1 == 3) ? hbsi[1][1][1] : tv1;
        float tv2 = hbsi[2][0][0];
        tv2 = (bj2 == 1) ? hbsi[2][0][1] : tv2;
        tv2 = (bj2 == 2) ? hbsi[2][1][0] : tv2;
        tv2 = (bj2 == 3) ? hbsi[2][1][1] : tv2;
        float tv3 = hbsi[3][0][0];
        tv3 = (bj3 == 1) ? hbsi[3][0][1] : tv3;
        tv3 = (bj3 == 2) ? hbsi[3][1][0] : tv3;
        tv3 = (bj3 == 3) ? hbsi[3][1][1] : tv3;
        float hs0 = rdlane_f(tv0, ow0);
        float hs1 = rdlane_f(tv1, ow1);
        float hs2 = rdlane_f(tv2, ow2);
        float hs3 = rdlane_f(tv3, ow3);
        Iv0[kk] = id0; Iv1[kk] = id1; Iv2[kk] = id2; Iv3[kk] = id3;
        // ---- quarter-select the uniform scalars for this lane's signal ----
        float hsel = (qt & 2) ? ((qt & 1) ? hs3 : hs2) : ((qt & 1) ? hs1 : hs0);
        int idxq = (qt & 2) ? ((qt & 1) ? id3 : id2) : ((qt & 1) ? id1 : id0);
        Ivq[kk] = idxq;
        // ---- Gs = G[Iv[j]][idx]: direct loads (L1-hot; round-3 pattern) ----
        float Gs0 = 0.f, Gs1 = 0.f, Gs2 = 0.f;
        if (kk > 0) Gs0 = G[(size_t)(Ivq[0] << 8) + idxq];
        if (kk > 1) Gs1 = G[(size_t)(Ivq[1] << 8) + idxq];
        if (kk > 2) Gs2 = G[(size_t)(Ivq[2] << 8) + idxq];
        // ---- Cholesky row update (round-3 verbatim; /L00==1 removed) ----
        if (kk == 1) {
            float cw0 = Gs0;
            float css = cw0 * cw0;
            float om = 1.0f - css;
            L10 = cw0;
            L11 = sqrtf(fmaxf(om, 1e-12f));
        }
        if (kk == 2) {
            float cw0 = Gs0;
            float ct = Gs1 - L10 * cw0;
            float cw1 = ct / L11;
            float css = cw0 * cw0;
            float cp = cw1 * cw1; css = css + cp;
            float om = 1.0f - css;
            L20 = cw0; L21 = cw1;
            L22 = sqrtf(fmaxf(om, 1e-12f));
        }
        if (kk == 3) {
            float cw0 = Gs0;
            float ct = Gs1 - L10 * cw0;
            float cw1 = ct / L11;
            float ca = L20 * cw0;
            float cp = L21 * cw1; ca = ca + cp;
            float ct3 = Gs2 - ca;
            float cw2 = ct3 / L22;
            float css = cw0 * cw0;
            cp = cw1 * cw1; css = css + cp;
            cp = cw2 * cw2; css = css + cp;
            float om = 1.0f - css;
            L30 = cw0; L31 = cw1; L32 = cw2;
            L33 = sqrtf(fmaxf(om, 1e-12f));
        }
        // ---- forward solve, incremental (row kk only) ----
        if (kk == 0) y0 = hsel;
        if (kk == 1) { float a = L10 * y0; y1 = (hsel - a) / L11; }
        if (kk == 2) { float a = L20 * y0; float p = L21 * y1; a = a + p;
                       y2 = (hsel - a) / L22; }
        if (kk == 3) { float a = L30 * y0; float p = L31 * y1; a = a + p;
                       p = L32 * y2; a = a + p;
                       y3 = (hsel - a) / L33; }
        // ---- backward solve L^T x = y (full, cc ascending) ----
        if (kk == 0) { x0 = y0; }
        if (kk == 1) {
            x1 = y1 / L11;
            float a = L10 * x1;
            x0 = y0 - a;
        }
        if (kk == 2) {
            x2 = y2 / L22;
            float a = L21 * x2;
            x1 = (y1 - a) / L11;
            a = L10 * x1;
            float p = L20 * x2; a = a + p;
            x0 = y0 - a;
        }
        if (kk == 3) {
            x3 = y3 / L33;
            float a = L32 * x3;
            x2 = (y2 - a) / L22;
            a = L21 * x2;
            float p = L31 * x3; a = a + p;
            x1 = (y1 - a) / L11;
            a = L10 * x1;
            p = L20 * x2; a = a + p;
            p = L30 * x3; a = a + p;
            x0 = y0 - a;
        }
        // ---- residual: h = h_bar - einsum(x, G[I]) (mul+add ascending jj) ----
        if (kk < 3) {
            // per-signal coefficient broadcasts from quarter-lead lanes
            float xb00 = rdlane_f(x0, 0),  xb10 = rdlane_f(x0, 16);
            float xb20 = rdlane_f(x0, 32), xb30 = rdlane_f(x0, 48);
            float xb01 = 0.f, xb11 = 0.f, xb21 = 0.f, xb31 = 0.f;
            float xb02 = 0.f, xb12 = 0.f, xb22 = 0.f, xb32 = 0.f;
            if (kk > 0) { xb01 = rdlane_f(x1, 0);  xb11 = rdlane_f(x1, 16);
                          xb21 = rdlane_f(x1, 32); xb31 = rdlane_f(x1, 48); }
            if (kk > 1) { xb02 = rdlane_f(x2, 0);  xb12 = rdlane_f(x2, 16);
                          xb22 = rdlane_f(x2, 32); xb32 = rdlane_f(x2, 48); }
            // G rows: uniform base + lane offset, all issued up-front
            const int l4 = 4 * lane;
            float4 R00 = *(const float4*)(G + ((size_t)Iv0[0] << 8) + l4);
            float4 R10 = *(const float4*)(G + ((size_t)Iv1[0] << 8) + l4);
            float4 R20 = *(const float4*)(G + ((size_t)Iv2[0] << 8) + l4);
            float4 R30 = *(const float4*)(G + ((size_t)Iv3[0] << 8) + l4);
            float4 R01, R11, R21, R31, R02, R12, R22, R32;
            if (kk > 0) {
                R01 = *(const float4*)(G + ((size_t)Iv0[1] << 8) + l4);
                R11 = *(const float4*)(G + ((size_t)Iv1[1] << 8) + l4);
                R21 = *(const float4*)(G + ((size_t)Iv2[1] << 8) + l4);
                R31 = *(const float4*)(G + ((size_t)Iv3[1] << 8) + l4);
            }
            if (kk > 1) {
                R02 = *(const float4*)(G + ((size_t)Iv0[2] << 8) + l4);
                R12 = *(const float4*)(G + ((size_t)Iv1[2] << 8) + l4);
                R22 = *(const float4*)(G + ((size_t)Iv2[2] << 8) + l4);
                R32 = *(const float4*)(G + ((size_t)Iv3[2] << 8) + l4);
            }
            {   // signal 0
                f2 bsa = (f2){xb00, xb00} * (f2){R00.x, R00.y};
                f2 bsb = (f2){xb00, xb00} * (f2){R00.z, R00.w};
                if (kk > 0) { f2 pa = (f2){xb01, xb01} * (f2){R01.x, R01.y}; bsa = bsa + pa;
                              f2 pb = (f2){xb01, xb01} * (f2){R01.z, R01.w}; bsb = bsb + pb; }
                if (kk > 1) { f2 pa = (f2){xb02, xb02} * (f2){R02.x, R02.y}; bsa = bsa + pa;
                              f2 pb = (f2){xb02, xb02} * (f2){R02.z, R02.w}; bsb = bsb + pb; }
                h0[0] = hbsi[0][0] - bsa;
                h0[1] = hbsi[0][1] - bsb;
            }
            {   // signal 1
                f2 bsa = (f2){xb10, xb10} * (f2){R10.x, R10.y};
                f2 bsb = (f2){xb10, xb10} * (f2){R10.z, R10.w};
                if (kk > 0) { f2 pa = (f2){xb11, xb11} * (f2){R11.x, R11.y}; bsa = bsa + pa;
                              f2 pb = (f2){xb11, xb11} * (f2){R11.z, R11.w}; bsb = bsb + pb; }
                if (kk > 1) { f2 pa = (f2){xb12, xb12} * (f2){R12.x, R12.y}; bsa = bsa + pa;
                              f2 pb = (f2){xb12, xb12} * (f2){R12.z, R12.w}; bsb = bsb + pb; }
                h1[0] = hbsi[1][0] - bsa;
                h1[1] = hbsi[1][1] - bsb;
            }
            {   // signal 2
                f2 bsa = (f2){xb20, xb20} * (f2){R20.x, R20.y};
                f2 bsb = (f2){xb20, xb20} * (f2){R20.z, R20.w};
                if (kk > 0) { f2 pa = (f2){xb21, xb21} * (f2){R21.x, R21.y}; bsa = bsa + pa;
                              f2 pb = (f2){xb21, xb21} * (f2){R21.z, R21.w}; bsb = bsb + pb; }
                if (kk > 1) { f2 pa = (f2){xb22, xb22} * (f2){R22.x, R22.y}; bsa = bsa + pa;
                              f2 pb = (f2){xb22, xb22} * (f2){R22.z, R22.w}; bsb = bsb + pb; }
                h2[0] = hbsi[2][0] - bsa;
                h2[1] = hbsi[2][1] - bsb;
            }
            {   // signal 3
                f2 bsa = (f2){xb30, xb30} * (f2){R30.x, R30.y};
                f2 bsb = (f2){xb30, xb30} * (f2){R30.z, R30.w};
                if (kk > 0) { f2 pa = (f2){xb31, xb31} * (f2){R31.x, R31.y}; bsa = bsa + pa;
                              f2 pb = (f2){xb31, xb31} * (f2){R31.z, R31.w}; bsb = bsb + pb; }
                if (kk > 1) { f2 pa = (f2){xb32, xb32} * (f2){R32.x, R32.y}; bsa = bsa + pa;
                              f2 pb = (f2){xb32, xb32} * (f2){R32.z, R32.w}; bsb = bsb + pb; }
                h3[0] = hbsi[3][0] - bsa;
                h3[1] = hbsi[3][1] - bsb;
            }
        }
    }
    // quarter-lead lanes (0,16,32,48) write their signal's coeffs + support
    if ((lane & 15) == 0) {
        int s = s0 + qt;
        xsv[0 * SIGS_B + s] = x0; xsv[1 * SIGS_B + s] = x1;
        xsv[2 * SIGS_B + s] = x2; xsv[3 * SIGS_B + s] = x3;
        qi[0 * SIGS_B + s] = Ivq[0]; qi[1 * SIGS_B + s] = Ivq[1];
        qi[2 * SIGS_B + s] = Ivq[2]; qi[3 * SIGS_B + s] = Ivq[3];
    }
}

// (256, 4): the proven clean allocator point (VGPR cap 128). Round-4/5
// lesson: tighter caps trigger 32/40-VGPR spill codegen.
__launch_bounds__(THREADS, 4)
__global__ void k_omp(const float* __restrict__ z,
                      const float* __restrict__ Dn_g,
                      const float* __restrict__ DnT_g,
                      const float* __restrict__ G,
                      double* __restrict__ loss_acc,
                      unsigned int* __restrict__ ctr,
                      float* __restrict__ zq,
                      float* __restrict__ loss_out)
{
    extern __shared__ char smem[];
    float* sig = (float*)(smem + LB_SIG);
    float* xsv = (float*)(smem + LB_XS);
    int* qi = (int*)(smem + LB_QI);
    double* red = (double*)(smem + LB_RED);

    int tid = threadIdx.x;
    int lane = tid & 63;
    int qt = lane >> 4;          // lane quarter = signal slot within quad
    int wid = tid >> 6;          // 0..3

    long sbase = (long)blockIdx.x * SIGS_B;  // 64 consecutive pixels, one batch b
    int b = (int)(sbase >> 12);
    int pl0 = (int)(sbase & 4095);
    const float* zb = z + ((size_t)b << 18) + pl0;
    // stage z_e -> sig[c][w], coalesced along w
    {
        int w = tid & (SIGS_B - 1);
        int g = tid >> 6;
#pragma unroll
        for (int i = 0; i < 16; i++) {
            int c = g * 16 + i;
            sig[c * SIGS_B + w] = zb[(size_t)c * 4096 + w];
        }
    }
    __syncthreads();

    // each wave: 16 signals in 2 groups of 8; h_bar = X^T Dn, fp32 fused-FMA
    // sequential over c ascending, packed as float2 -> v_pk_fma_f32.
    for (int g2 = 0; g2 < 2; g2++) {
        int s0 = wid * 16 + g2 * 8;
        f2 hb[8][2];
#pragma unroll
        for (int a = 0; a < 8; a++) {
            hb[a][0] = (f2){0.0f, 0.0f};
            hb[a][1] = (f2){0.0f, 0.0f};
        }
#pragma unroll 8
        for (int c = 0; c < DIM; c++) {
            float4 sva = *(const float4*)(sig + c * SIGS_B + s0);
            float4 svb = *(const float4*)(sig + c * SIGS_B + s0 + 4);
            float s8[8] = {sva.x, sva.y, sva.z, sva.w, svb.x, svb.y, svb.z, svb.w};
            float4 dv = *(const float4*)(Dn_g + c * NEMB + 4 * lane);
            f2 d0; d0.x = dv.x; d0.y = dv.y;
            f2 d1; d1.x = dv.z; d1.y = dv.w;
#pragma unroll
            for (int a = 0; a < 8; a++) {
                f2 sa = {s8[a], s8[a]};
                hb[a][0] = __builtin_elementwise_fma(sa, d0, hb[a][0]);
                hb[a][1] = __builtin_elementwise_fma(sa, d1, hb[a][1]);
            }
        }
        omp_quad(hb,     lane, qt, G, xsv, qi, s0);
        omp_quad(hb + 4, lane, qt, G, xsv, qi, s0 + 4);
    }
    __syncthreads();

    // thread-parallel mu-law quantize of all 256 coeffs (one per thread)
    {
        int jq = tid >> 6;
        int wq = tid & (SIGS_B - 1);
        xsv[jq * SIGS_B + wq] = quant_decode(xsv[jq * SIGS_B + wq]);
    }
    __syncthreads();

    // store phase: recon (einsum order: mul+add, k ascending, no fma),
    // gathers vectorized via DnT (DnT[i][c] == Dn[c][i], bit-identical).
    double lsum = 0.0;
    float* zqb = zq + ((size_t)b << 18) + pl0;
    {
#pragma clang fp contract(off)
        int w = tid & (SIGS_B - 1);
        int g = tid >> 6;
        float q0 = xsv[0 * SIGS_B + w], q1 = xsv[1 * SIGS_B + w];
        float q2 = xsv[2 * SIGS_B + w], q3 = xsv[3 * SIGS_B + w];
        int i0 = qi[0 * SIGS_B + w], i1 = qi[1 * SIGS_B + w];
        int i2 = qi[2 * SIGS_B + w], i3 = qi[3 * SIGS_B + w];
        const float* t0p = DnT_g + (i0 << 6) + (g << 4);
        const float* t1p = DnT_g + (i1 << 6) + (g << 4);
        const float* t2p = DnT_g + (i2 << 6) + (g << 4);
        const float* t3p = DnT_g + (i3 << 6) + (g << 4);
#pragma unroll
        for (int cb = 0; cb < 4; cb++) {
            float4 d0 = *(const float4*)(t0p + 4 * cb);
            float4 d1 = *(const float4*)(t1p + 4 * cb);
            float4 d2 = *(const float4*)(t2p + 4 * cb);
            float4 d3 = *(const float4*)(t3p + 4 * cb);
#pragma unroll
            for (int u = 0; u < 4; u++) {
                int c = (g << 4) + (cb << 2) + u;
                float e0 = (u == 0) ? d0.x : (u == 1) ? d0.y : (u == 2) ? d0.z : d0.w;
                float e1 = (u == 0) ? d1.x : (u == 1) ? d1.y : (u == 2) ? d1.z : d1.w;
                float e2 = (u == 0) ? d2.x : (u == 1) ? d2.y : (u == 2) ? d2.z : d2.w;
                float e3 = (u == 0) ? d3.x : (u == 1) ? d3.y : (u == 2) ? d3.z : d3.w;
                float p0 = q0 * e0;
                float p1 = q1 * e1;
                float p2 = q2 * e2;
                float p3 = q3 * e3;
                float r = p0 + p1;
                r = r + p2;
                r = r + p3;
                float zev = sig[c * SIGS_B + w];
                float d = r - zev;
                float zqv = zev + d;           // z_q = z_e + (recon - z_e)
                lsum += (double)d * (double)d;
                zqb[(size_t)c * 4096 + w] = zqv;
            }
        }
    }
#pragma unroll
    for (int off = 32; off > 0; off >>= 1) lsum += __shfl_xor(lsum, off);
    if (lane == 0) red[wid] = lsum;
    __syncthreads();
    if (tid == 0) {
        double t = 0.0;
#pragma unroll
        for (int i = 0; i < 4; i++) t += red[i];
        atomicAdd(loss_acc, t);
        __threadfence();
        unsigned int done = atomicAdd(ctr, 1u);
        if (done == GRID - 1) {
            double m = atomicAdd(loss_acc, 0.0) / 8388608.0;
            loss_out[0] = (float)(m + 0.25 * m);
        }
    }
}

extern "C" void kernel_launch(void* const* d_in, const int* in_sizes, int n_in,
                              void* d_out, int out_size, void* d_ws, size_t ws_size,
                              hipStream_t stream)
{
    const float* z = (const float*)d_in[0];
    const float* D = (const float*)d_in[1];
    float* out = (float*)d_out;
    char* ws = (char*)d_ws;
    double* loss_acc = (double*)ws;                       // 8 B
    unsigned int* ctr = (unsigned int*)(ws + 8);          // 4 B
    float* Dn = (float*)(ws + 256);                       // 64x256 f32
    float* G = (float*)(ws + 256 + 65536);                // 256x256 f32
    float* DnT = (float*)(ws + 256 + 65536 + 262144);     // 256x64 f32

    k_ng<<<NEMB, NEMB, 0, stream>>>(D, Dn, DnT, G, loss_acc, ctr);
    hipFuncSetAttribute(reinterpret_cast<const void*>(k_omp),
                        hipFuncAttributeMaxDynamicSharedMemorySize, LDS_BYTES);
    k_omp<<<GRID, THREADS, LDS_BYTES, stream>>>(z, Dn, DnT, G, loss_acc, ctr, out, out + 8388608);
    (void)in_sizes; (void)n_in; (void)out_size; (void)ws_size;
}

// Round 8
// 295.768 us; speedup vs baseline: 2.1794x; 1.0126x over previous
//
#include <hip/hip_runtime.h>
#include <math.h>

#define NEMB 256
#define DIM 64
#define SIGS_B 64                 // signals per block
#define THREADS 256               // 4 waves per block
#define NSIG 131072
#define GRID (NSIG / SIGS_B)      // 2048

#define LOG1P50 3.9318256327243257        // np.log1p(50.0), f64
#define INV_MU_F ((float)(1.0 / LOG1P50)) // fp32-rounded scalar, as numpy uses
#define TWO15_F ((float)(2.0 / 15.0))

// dynamic LDS layout (byte offsets) — Dn NOT staged (L2-hot from global)
#define LB_SIG   0          // 16384 B : sig f32 [c][w]  (64 x 64)
#define LB_XS    16384      // 1024 B  : raw coeffs f32 [4][SIGS_B]
#define LB_QI    17408      // 1024 B  : qi i32 [4][SIGS_B]
#define LB_RED   18432      // 32 B    : per-wave loss partials (f64)
#define LDS_BYTES 18464

typedef float f2 __attribute__((ext_vector_type(2)));

__device__ __forceinline__ float rdlane_f(float v, int lane)
{
    return __builtin_bit_cast(float, __builtin_amdgcn_readlane(__builtin_bit_cast(int, v), lane));
}

template<int CTRL>
__device__ __forceinline__ float dpp_fmax(float m)
{
    int sh = __builtin_amdgcn_update_dpp(0, __builtin_bit_cast(int, m), CTRL, 0xf, 0xf, true);
    return fmaxf(m, __builtin_bit_cast(float, sh));
}

// wave-wide max of non-negative values; valid in lane 63. Pure VALU (DPP).
__device__ __forceinline__ float wave_max_nn(float v)
{
    v = dpp_fmax<0x111>(v);   // row_shr:1
    v = dpp_fmax<0x112>(v);   // row_shr:2
    v = dpp_fmax<0x114>(v);   // row_shr:4
    v = dpp_fmax<0x118>(v);   // row_shr:8  -> lane 15/31/47/63 = row max
    v = dpp_fmax<0x142>(v);   // row_bcast:15 -> lane 31/63 = half max
    v = dpp_fmax<0x143>(v);   // row_bcast:31 -> lane 63 = wave max
    return v;
}

// Fused normalize + gram (+ DnT transpose for the store-phase vector gathers).
__global__ void k_ng(const float* __restrict__ D, float* __restrict__ Dn,
                     float* __restrict__ DnT, float* __restrict__ G,
                     double* __restrict__ loss_acc, unsigned int* __restrict__ ctr)
{
#pragma clang fp contract(off)
    __shared__ float nrmS[NEMB];
    __shared__ float coli[DIM];
    int i = blockIdx.x, j = threadIdx.x;
    if (i == 0 && j == 0) { loss_acc[0] = 0.0; ctr[0] = 0u; }
    float ss = 0.0f;
    for (int c = 0; c < DIM; c++) {
        float v = D[c * NEMB + j];
        float sq = v * v;
        ss = ss + sq;
    }
    float nrm = fmaxf(sqrtf(ss), 1e-10f);
    nrmS[j] = nrm;
    __syncthreads();
    if (j < DIM) {
        float dni = D[j * NEMB + i] / nrmS[i];
        coli[j] = dni;
        Dn[j * NEMB + i] = dni;         // block i owns Dn column i
        DnT[i * DIM + j] = dni;         // and DnT row i (same bits)
    }
    __syncthreads();
    float s = 0.0f;
#pragma unroll 8
    for (int c = 0; c < DIM; c++) {
        float dnj = D[c * NEMB + j] / nrm;     // rounds identically to Dn[c][j]
        s = fmaf(coli[c], dnj, s);
    }
    G[i * NEMB + j] = s;
}

// mu-law quantize+decode, all fp32, numpy op-for-op (no fusion)
__device__ __forceinline__ float quant_decode(float coeff)
{
#pragma clang fp contract(off)
    float c = fminf(fmaxf(coeff, -3.0f), 3.0f) / 3.0f;
    float ac = fabsf(c);
    float sgn = (c > 0.0f) ? 1.0f : ((c < 0.0f) ? -1.0f : 0.0f);
    float l = log1pf(ac * 50.0f);
    float enc = (sgn * l) * INV_MU_F;
    float scaled = (enc + 1.0f) * 7.5f;
    int bin = (int)rintf(scaled);              // round-half-even == np.round
    bin = bin < 0 ? 0 : (bin > 15 ? 15 : bin);
    float t = (float)bin * TWO15_F;
    float zv = t - 1.0f;
    float az = fabsf(zv);
    float sz = (zv > 0.0f) ? 1.0f : ((zv < 0.0f) ? -1.0f : 0.0f);
    float e = expm1f(az / INV_MU_F);
    return (sz * (e / 50.0f)) * 3.0f;
}

// FOUR signals' OMP (K=4) per call — IDENTICAL arithmetic to round 7.
// KEY CHANGE: hb passed as array REFERENCE with template-constant base B.
// Round-7 passed hb+4 by pointer, which defeated SROA: the compiler spilled
// the whole hb array to scratch at the call boundary and the OMP phase read
// hbsi from scratch for the rest of the kernel (~64MB/launch of excess HBM
// writes: WRITE_SIZE 98MB vs 32MB ideal). Constant indices -> hb stays in
// VGPRs end-to-end.
template<int B>
__device__ __forceinline__ void omp_quad(const f2 (&hb)[8][2], int lane, int qt,
                                         const float* __restrict__ G,
                                         float* __restrict__ xsv,
                                         int* __restrict__ qi, int s0)
{
#pragma clang fp contract(off)
    f2 h0[2] = {hb[B + 0][0], hb[B + 0][1]};
    f2 h1[2] = {hb[B + 1][0], hb[B + 1][1]};
    f2 h2[2] = {hb[B + 2][0], hb[B + 2][1]};
    f2 h3[2] = {hb[B + 3][0], hb[B + 3][1]};
    int m40 = 0, m41 = 0, m42 = 0, m43 = 0;
    int Iv0[4], Iv1[4], Iv2[4], Iv3[4];   // uniform support indices (const-idx)
    int Ivq[4];                            // own quarter's support indices
    float L10, L11, L20, L21, L22, L30, L31, L32, L33;
    float y0, y1, y2, y3;
    float x0 = 0.f, x1 = 0.f, x2 = 0.f, x3 = 0.f;
#pragma unroll
    for (int kk = 0; kk < 4; kk++) {
        // ---- per-lane best of own 4 atoms, 4 independent chains ----
        float bv0 = -1.f, bv1 = -1.f, bv2 = -1.f, bv3 = -1.f;
        int bj0 = 0, bj1 = 0, bj2 = 0, bj3 = 0;
#pragma unroll
        for (int j = 0; j < 4; j++) {
            float a0 = (m40 & (1 << j)) ? 0.f : fabsf(h0[j >> 1][j & 1]);
            if (a0 > bv0) { bv0 = a0; bj0 = j; }
            float a1 = (m41 & (1 << j)) ? 0.f : fabsf(h1[j >> 1][j & 1]);
            if (a1 > bv1) { bv1 = a1; bj1 = j; }
            float a2 = (m42 & (1 << j)) ? 0.f : fabsf(h2[j >> 1][j & 1]);
            if (a2 > bv2) { bv2 = a2; bj2 = j; }
            float a3 = (m43 & (1 << j)) ? 0.f : fabsf(h3[j >> 1][j & 1]);
            if (a3 > bv3) { bv3 = a3; bj3 = j; }
        }
        // ---- wave max (value only) x4, then first-lane tie-break ----
        float r0 = wave_max_nn(bv0);
        float r1 = wave_max_nn(bv1);
        float r2 = wave_max_nn(bv2);
        float r3 = wave_max_nn(bv3);
        float vm0 = rdlane_f(r0, 63), vm1 = rdlane_f(r1, 63);
        float vm2 = rdlane_f(r2, 63), vm3 = rdlane_f(r3, 63);
        unsigned long long bl0 = __ballot(bv0 == vm0);
        unsigned long long bl1 = __ballot(bv1 == vm1);
        unsigned long long bl2 = __ballot(bv2 == vm2);
        unsigned long long bl3 = __ballot(bv3 == vm3);
        int ow0 = __ffsll((long long)bl0) - 1;
        int ow1 = __ffsll((long long)bl1) - 1;
        int ow2 = __ffsll((long long)bl2) - 1;
        int ow3 = __ffsll((long long)bl3) - 1;
        int bo0 = __builtin_amdgcn_readlane(bj0, ow0);
        int bo1 = __builtin_amdgcn_readlane(bj1, ow1);
        int bo2 = __builtin_amdgcn_readlane(bj2, ow2);
        int bo3 = __builtin_amdgcn_readlane(bj3, ow3);
        int id0 = 4 * ow0 + bo0;           // uniform
        int id1 = 4 * ow1 + bo1;
        int id2 = 4 * ow2 + bo2;
        int id3 = 4 * ow3 + bo3;
        m40 |= (lane == ow0) ? (1 << bo0) : 0;
        m41 |= (lane == ow1) ? (1 << bo1) : 0;
        m42 |= (lane == ow2) ? (1 << bo2) : 0;
        m43 |= (lane == ow3) ? (1 << bo3) : 0;
        // ---- original h_bar at selected atom (local tree + owner readlane) ----
        float tv0 = hb[B + 0][0][0];
        tv0 = (bj0 == 1) ? hb[B + 0][0][1] : tv0;
        tv0 = (bj0 == 2) ? hb[B + 0][1][0] : tv0;
        tv0 = (bj0 == 3) ? hb[B + 0][1][1] : tv0;
        float tv1 = hb[B + 1][0][0];
        tv1 = (bj1 == 1) ? hb[B + 1][0][1] : tv1;
        tv1 = (bj1 == 2) ? hb[B + 1][1][0] : tv1;
        tv1 = (bj1 == 3) ? hb[B + 1][1][1] : tv1;
        float tv2 = hb[B + 2][0][0];
        tv2 = (bj2 == 1) ? hb[B + 2][0][1] : tv2;
        tv2 = (bj2 == 2) ? hb[B + 2][1][0] : tv2;
        tv2 = (bj2 == 3) ? hb[B + 2][1][1] : tv2;
        float tv3 = hb[B + 3][0][0];
        tv3 = (bj3 == 1) ? hb[B + 3][0][1] : tv3;
        tv3 = (bj3 == 2) ? hb[B + 3][1][0] : tv3;
        tv3 = (bj3 == 3) ? hb[B + 3][1][1] : tv3;
        float hs0 = rdlane_f(tv0, ow0);
        float hs1 = rdlane_f(tv1, ow1);
        float hs2 = rdlane_f(tv2, ow2);
        float hs3 = rdlane_f(tv3, ow3);
        Iv0[kk] = id0; Iv1[kk] = id1; Iv2[kk] = id2; Iv3[kk] = id3;
        // ---- quarter-select the uniform scalars for this lane's signal ----
        float hsel = (qt & 2) ? ((qt & 1) ? hs3 : hs2) : ((qt & 1) ? hs1 : hs0);
        int idxq = (qt & 2) ? ((qt & 1) ? id3 : id2) : ((qt & 1) ? id1 : id0);
        Ivq[kk] = idxq;
        // ---- Gs = G[Iv[j]][idx]: direct loads (L1-hot; round-3 pattern) ----
        float Gs0 = 0.f, Gs1 = 0.f, Gs2 = 0.f;
        if (kk > 0) Gs0 = G[(size_t)(Ivq[0] << 8) + idxq];
        if (kk > 1) Gs1 = G[(size_t)(Ivq[1] << 8) + idxq];
        if (kk > 2) Gs2 = G[(size_t)(Ivq[2] << 8) + idxq];
        // ---- Cholesky row update (round-3 verbatim; /L00==1 removed) ----
        if (kk == 1) {
            float cw0 = Gs0;
            float css = cw0 * cw0;
            float om = 1.0f - css;
            L10 = cw0;
            L11 = sqrtf(fmaxf(om, 1e-12f));
        }
        if (kk == 2) {
            float cw0 = Gs0;
            float ct = Gs1 - L10 * cw0;
            float cw1 = ct / L11;
            float css = cw0 * cw0;
            float cp = cw1 * cw1; css = css + cp;
            float om = 1.0f - css;
            L20 = cw0; L21 = cw1;
            L22 = sqrtf(fmaxf(om, 1e-12f));
        }
        if (kk == 3) {
            float cw0 = Gs0;
            float ct = Gs1 - L10 * cw0;
            float cw1 = ct / L11;
            float ca = L20 * cw0;
            float cp = L21 * cw1; ca = ca + cp;
            float ct3 = Gs2 - ca;
            float cw2 = ct3 / L22;
            float css = cw0 * cw0;
            cp = cw1 * cw1; css = css + cp;
            cp = cw2 * cw2; css = css + cp;
            float om = 1.0f - css;
            L30 = cw0; L31 = cw1; L32 = cw2;
            L33 = sqrtf(fmaxf(om, 1e-12f));
        }
        // ---- forward solve, incremental (row kk only) ----
        if (kk == 0) y0 = hsel;
        if (kk == 1) { float a = L10 * y0; y1 = (hsel - a) / L11; }
        if (kk == 2) { float a = L20 * y0; float p = L21 * y1; a = a + p;
                       y2 = (hsel - a) / L22; }
        if (kk == 3) { float a = L30 * y0; float p = L31 * y1; a = a + p;
                       p = L32 * y2; a = a + p;
                       y3 = (hsel - a) / L33; }
        // ---- backward solve L^T x = y (full, cc ascending) ----
        if (kk == 0) { x0 = y0; }
        if (kk == 1) {
            x1 = y1 / L11;
            float a = L10 * x1;
            x0 = y0 - a;
        }
        if (kk == 2) {
            x2 = y2 / L22;
            float a = L21 * x2;
            x1 = (y1 - a) / L11;
            a = L10 * x1;
            float p = L20 * x2; a = a + p;
            x0 = y0 - a;
        }
        if (kk == 3) {
            x3 = y3 / L33;
            float a = L32 * x3;
            x2 = (y2 - a) / L22;
            a = L21 * x2;
            float p = L31 * x3; a = a + p;
            x1 = (y1 - a) / L11;
            a = L10 * x1;
            p = L20 * x2; a = a + p;
            p = L30 * x3; a = a + p;
            x0 = y0 - a;
        }
        // ---- residual: h = h_bar - einsum(x, G[I]) (mul+add ascending jj) ----
        if (kk < 3) {
            // per-signal coefficient broadcasts from quarter-lead lanes
            float xb00 = rdlane_f(x0, 0),  xb10 = rdlane_f(x0, 16);
            float xb20 = rdlane_f(x0, 32), xb30 = rdlane_f(x0, 48);
            float xb01 = 0.f, xb11 = 0.f, xb21 = 0.f, xb31 = 0.f;
            float xb02 = 0.f, xb12 = 0.f, xb22 = 0.f, xb32 = 0.f;
            if (kk > 0) { xb01 = rdlane_f(x1, 0);  xb11 = rdlane_f(x1, 16);
                          xb21 = rdlane_f(x1, 32); xb31 = rdlane_f(x1, 48); }
            if (kk > 1) { xb02 = rdlane_f(x2, 0);  xb12 = rdlane_f(x2, 16);
                          xb22 = rdlane_f(x2, 32); xb32 = rdlane_f(x2, 48); }
            // G rows: uniform base + lane offset, all issued up-front
            const int l4 = 4 * lane;
            float4 R00 = *(const float4*)(G + ((size_t)Iv0[0] << 8) + l4);
            float4 R10 = *(const float4*)(G + ((size_t)Iv1[0] << 8) + l4);
            float4 R20 = *(const float4*)(G + ((size_t)Iv2[0] << 8) + l4);
            float4 R30 = *(const float4*)(G + ((size_t)Iv3[0] << 8) + l4);
            float4 R01, R11, R21, R31, R02, R12, R22, R32;
            if (kk > 0) {
                R01 = *(const float4*)(G + ((size_t)Iv0[1] << 8) + l4);
                R11 = *(const float4*)(G + ((size_t)Iv1[1] << 8) + l4);
                R21 = *(const float4*)(G + ((size_t)Iv2[1] << 8) + l4);
                R31 = *(const float4*)(G + ((size_t)Iv3[1] << 8) + l4);
            }
            if (kk > 1) {
                R02 = *(const float4*)(G + ((size_t)Iv0[2] << 8) + l4);
                R12 = *(const float4*)(G + ((size_t)Iv1[2] << 8) + l4);
                R22 = *(const float4*)(G + ((size_t)Iv2[2] << 8) + l4);
                R32 = *(const float4*)(G + ((size_t)Iv3[2] << 8) + l4);
            }
            {   // signal 0
                f2 bsa = (f2){xb00, xb00} * (f2){R00.x, R00.y};
                f2 bsb = (f2){xb00, xb00} * (f2){R00.z, R00.w};
                if (kk > 0) { f2 pa = (f2){xb01, xb01} * (f2){R01.x, R01.y}; bsa = bsa + pa;
                              f2 pb = (f2){xb01, xb01} * (f2){R01.z, R01.w}; bsb = bsb + pb; }
                if (kk > 1) { f2 pa = (f2){xb02, xb02} * (f2){R02.x, R02.y}; bsa = bsa + pa;
                              f2 pb = (f2){xb02, xb02} * (f2){R02.z, R02.w}; bsb = bsb + pb; }
                h0[0] = hb[B + 0][0] - bsa;
                h0[1] = hb[B + 0][1] - bsb;
            }
            {   // signal 1
                f2 bsa = (f2){xb10, xb10} * (f2){R10.x, R10.y};
                f2 bsb = (f2){xb10, xb10} * (f2){R10.z, R10.w};
                if (kk > 0) { f2 pa = (f2){xb11, xb11} * (f2){R11.x, R11.y}; bsa = bsa + pa;
                              f2 pb = (f2){xb11, xb11} * (f2){R11.z, R11.w}; bsb = bsb + pb; }
                if (kk > 1) { f2 pa = (f2){xb12, xb12} * (f2){R12.x, R12.y}; bsa = bsa + pa;
                              f2 pb = (f2){xb12, xb12} * (f2){R12.z, R12.w}; bsb = bsb + pb; }
                h1[0] = hb[B + 1][0] - bsa;
                h1[1] = hb[B + 1][1] - bsb;
            }
            {   // signal 2
                f2 bsa = (f2){xb20, xb20} * (f2){R20.x, R20.y};
                f2 bsb = (f2){xb20, xb20} * (f2){R20.z, R20.w};
                if (kk > 0) { f2 pa = (f2){xb21, xb21} * (f2){R21.x, R21.y}; bsa = bsa + pa;
                              f2 pb = (f2){xb21, xb21} * (f2){R21.z, R21.w}; bsb = bsb + pb; }
                if (kk > 1) { f2 pa = (f2){xb22, xb22} * (f2){R22.x, R22.y}; bsa = bsa + pa;
                              f2 pb = (f2){xb22, xb22} * (f2){R22.z, R22.w}; bsb = bsb + pb; }
                h2[0] = hb[B + 2][0] - bsa;
                h2[1] = hb[B + 2][1] - bsb;
            }
            {   // signal 3
                f2 bsa = (f2){xb30, xb30} * (f2){R30.x, R30.y};
                f2 bsb = (f2){xb30, xb30} * (f2){R30.z, R30.w};
                if (kk > 0) { f2 pa = (f2){xb31, xb31} * (f2){R31.x, R31.y}; bsa = bsa + pa;
                              f2 pb = (f2){xb31, xb31} * (f2){R31.z, R31.w}; bsb = bsb + pb; }
                if (kk > 1) { f2 pa = (f2){xb32, xb32} * (f2){R32.x, R32.y}; bsa = bsa + pa;
                              f2 pb = (f2){xb32, xb32} * (f2){R32.z, R32.w}; bsb = bsb + pb; }
                h3[0] = hb[B + 3][0] - bsa;
                h3[1] = hb[B + 3][1] - bsb;
            }
        }
    }
    // quarter-lead lanes (0,16,32,48) write their signal's coeffs + support
    if ((lane & 15) == 0) {
        int s = s0 + qt;
        xsv[0 * SIGS_B + s] = x0; xsv[1 * SIGS_B + s] = x1;
        xsv[2 * SIGS_B + s] = x2; xsv[3 * SIGS_B + s] = x3;
        qi[0 * SIGS_B + s] = Ivq[0]; qi[1 * SIGS_B + s] = Ivq[1];
        qi[2 * SIGS_B + s] = Ivq[2]; qi[3 * SIGS_B + s] = Ivq[3];
    }
}

// (256, 4): the proven clean allocator point (VGPR cap 128). Round-4/5
// lesson: tighter caps trigger 32/40-VGPR spill codegen.
__launch_bounds__(THREADS, 4)
__global__ void k_omp(const float* __restrict__ z,
                      const float* __restrict__ Dn_g,
                      const float* __restrict__ DnT_g,
                      const float* __restrict__ G,
                      double* __restrict__ loss_acc,
                      unsigned int* __restrict__ ctr,
                      float* __restrict__ zq,
                      float* __restrict__ loss_out)
{
    extern __shared__ char smem[];
    float* sig = (float*)(smem + LB_SIG);
    float* xsv = (float*)(smem + LB_XS);
    int* qi = (int*)(smem + LB_QI);
    double* red = (double*)(smem + LB_RED);

    int tid = threadIdx.x;
    int lane = tid & 63;
    int qt = lane >> 4;          // lane quarter = signal slot within quad
    int wid = tid >> 6;          // 0..3

    long sbase = (long)blockIdx.x * SIGS_B;  // 64 consecutive pixels, one batch b
    int b = (int)(sbase >> 12);
    int pl0 = (int)(sbase & 4095);
    const float* zb = z + ((size_t)b << 18) + pl0;
    // stage z_e -> sig[c][w], coalesced along w
    {
        int w = tid & (SIGS_B - 1);
        int g = tid >> 6;
#pragma unroll
        for (int i = 0; i < 16; i++) {
            int c = g * 16 + i;
            sig[c * SIGS_B + w] = zb[(size_t)c * 4096 + w];
        }
    }
    __syncthreads();

    // each wave: 16 signals in 2 groups of 8; h_bar = X^T Dn, fp32 fused-FMA
    // sequential over c ascending, packed as float2 -> v_pk_fma_f32.
    for (int g2 = 0; g2 < 2; g2++) {
        int s0 = wid * 16 + g2 * 8;
        f2 hb[8][2];
#pragma unroll
        for (int a = 0; a < 8; a++) {
            hb[a][0] = (f2){0.0f, 0.0f};
            hb[a][1] = (f2){0.0f, 0.0f};
        }
#pragma unroll 8
        for (int c = 0; c < DIM; c++) {
            float4 sva = *(const float4*)(sig + c * SIGS_B + s0);
            float4 svb = *(const float4*)(sig + c * SIGS_B + s0 + 4);
            float s8[8] = {sva.x, sva.y, sva.z, sva.w, svb.x, svb.y, svb.z, svb.w};
            float4 dv = *(const float4*)(Dn_g + c * NEMB + 4 * lane);
            f2 d0; d0.x = dv.x; d0.y = dv.y;
            f2 d1; d1.x = dv.z; d1.y = dv.w;
#pragma unroll
            for (int a = 0; a < 8; a++) {
                f2 sa = {s8[a], s8[a]};
                hb[a][0] = __builtin_elementwise_fma(sa, d0, hb[a][0]);
                hb[a][1] = __builtin_elementwise_fma(sa, d1, hb[a][1]);
            }
        }
        omp_quad<0>(hb, lane, qt, G, xsv, qi, s0);
        omp_quad<4>(hb, lane, qt, G, xsv, qi, s0 + 4);
    }
    __syncthreads();

    // thread-parallel mu-law quantize of all 256 coeffs (one per thread)
    {
        int jq = tid >> 6;
        int wq = tid & (SIGS_B - 1);
        xsv[jq * SIGS_B + wq] = quant_decode(xsv[jq * SIGS_B + wq]);
    }
    __syncthreads();

    // store phase: recon (einsum order: mul+add, k ascending, no fma),
    // gathers vectorized via DnT (DnT[i][c] == Dn[c][i], bit-identical).
    double lsum = 0.0;
    float* zqb = zq + ((size_t)b << 18) + pl0;
    {
#pragma clang fp contract(off)
        int w = tid & (SIGS_B - 1);
        int g = tid >> 6;
        float q0 = xsv[0 * SIGS_B + w], q1 = xsv[1 * SIGS_B + w];
        float q2 = xsv[2 * SIGS_B + w], q3 = xsv[3 * SIGS_B + w];
        int i0 = qi[0 * SIGS_B + w], i1 = qi[1 * SIGS_B + w];
        int i2 = qi[2 * SIGS_B + w], i3 = qi[3 * SIGS_B + w];
        const float* t0p = DnT_g + (i0 << 6) + (g << 4);
        const float* t1p = DnT_g + (i1 << 6) + (g << 4);
        const float* t2p = DnT_g + (i2 << 6) + (g << 4);
        const float* t3p = DnT_g + (i3 << 6) + (g << 4);
#pragma unroll
        for (int cb = 0; cb < 4; cb++) {
            float4 d0 = *(const float4*)(t0p + 4 * cb);
            float4 d1 = *(const float4*)(t1p + 4 * cb);
            float4 d2 = *(const float4*)(t2p + 4 * cb);
            float4 d3 = *(const float4*)(t3p + 4 * cb);
#pragma unroll
            for (int u = 0; u < 4; u++) {
                int c = (g << 4) + (cb << 2) + u;
                float e0 = (u == 0) ? d0.x : (u == 1) ? d0.y : (u == 2) ? d0.z : d0.w;
                float e1 = (u == 0) ? d1.x : (u == 1) ? d1.y : (u == 2) ? d1.z : d1.w;
                float e2 = (u == 0) ? d2.x : (u == 1) ? d2.y : (u == 2) ? d2.z : d2.w;
                float e3 = (u == 0) ? d3.x : (u == 1) ? d3.y : (u == 2) ? d3.z : d3.w;
                float p0 = q0 * e0;
                float p1 = q1 * e1;
                float p2 = q2 * e2;
                float p3 = q3 * e3;
                float r = p0 + p1;
                r = r + p2;
                r = r + p3;
                float zev = sig[c * SIGS_B + w];
                float d = r - zev;
                float zqv = zev + d;           // z_q = z_e + (recon - z_e)
                lsum += (double)d * (double)d;
                zqb[(size_t)c * 4096 + w] = zqv;
            }
        }
    }
#pragma unroll
    for (int off = 32; off > 0; off >>= 1) lsum += __shfl_xor(lsum, off);
    if (lane == 0) red[wid] = lsum;
    __syncthreads();
    if (tid == 0) {
        double t = 0.0;
#pragma unroll
        for (int i = 0; i < 4; i++) t += red[i];
        atomicAdd(loss_acc, t);
        __threadfence();
        unsigned int done = atomicAdd(ctr, 1u);
        if (done == GRID - 1) {
            double m = atomicAdd(loss_acc, 0.0) / 8388608.0;
            loss_out[0] = (float)(m + 0.25 * m);
        }
    }
}

extern "C" void kernel_launch(void* const* d_in, const int* in_sizes, int n_in,
                              void* d_out, int out_size, void* d_ws, size_t ws_size,
                              hipStream_t stream)
{
    const float* z = (const float*)d_in[0];
    const float* D = (const float*)d_in[1];
    float* out = (float*)d_out;
    char* ws = (char*)d_ws;
    double* loss_acc = (double*)ws;                       // 8 B
    unsigned int* ctr = (unsigned int*)(ws + 8);          // 4 B
    float* Dn = (float*)(ws + 256);                       // 64x256 f32
    float* G = (float*)(ws + 256 + 65536);                // 256x256 f32
    float* DnT = (float*)(ws + 256 + 65536 + 262144);     // 256x64 f32

    k_ng<<<NEMB, NEMB, 0, stream>>>(D, Dn, DnT, G, loss_acc, ctr);
    hipFuncSetAttribute(reinterpret_cast<const void*>(k_omp),
                        hipFuncAttributeMaxDynamicSharedMemorySize, LDS_BYTES);
    k_omp<<<GRID, THREADS, LDS_BYTES, stream>>>(z, Dn, DnT, G, loss_acc, ctr, out, out + 8388608);
    (void)in_sizes; (void)n_in; (void)out_size; (void)ws_size;
}

// Round 10
// 262.487 us; speedup vs baseline: 2.4557x; 1.1268x over previous
//
#include <hip/hip_runtime.h>
#include <math.h>

#define NEMB 256
#define DIM 64
#define SIGS_B 64                 // signals per block
#define THREADS 256               // 4 waves per block
#define NSIG 131072
#define GRID (NSIG / SIGS_B)      // 2048

#define LOG1P50 3.9318256327243257        // np.log1p(50.0), f64
#define INV_MU_F ((float)(1.0 / LOG1P50)) // fp32-rounded scalar, as numpy uses
#define TWO15_F ((float)(2.0 / 15.0))

// dynamic LDS layout (byte offsets) — Dn NOT staged (L2-hot from global)
#define LB_SIG   0          // 16384 B : sig f32 [c][w]  (64 x 64)
#define LB_XS    16384      // 1024 B  : raw coeffs f32 [4][SIGS_B]
#define LB_QI    17408      // 1024 B  : qi i32 [4][SIGS_B]
#define LB_RED   18432      // 32 B    : per-wave loss partials (f64)
#define LDS_BYTES 18464

typedef float f2 __attribute__((ext_vector_type(2)));

__device__ __forceinline__ float rdlane_f(float v, int lane)
{
    return __builtin_bit_cast(float, __builtin_amdgcn_readlane(__builtin_bit_cast(int, v), lane));
}

template<int CTRL>
__device__ __forceinline__ float dpp_fmax(float m)
{
    int sh = __builtin_amdgcn_update_dpp(0, __builtin_bit_cast(int, m), CTRL, 0xf, 0xf, true);
    return fmaxf(m, __builtin_bit_cast(float, sh));
}

// wave-wide max of non-negative values; valid in lane 63. Pure VALU (DPP).
__device__ __forceinline__ float wave_max_nn(float v)
{
    v = dpp_fmax<0x111>(v);   // row_shr:1
    v = dpp_fmax<0x112>(v);   // row_shr:2
    v = dpp_fmax<0x114>(v);   // row_shr:4
    v = dpp_fmax<0x118>(v);   // row_shr:8  -> lane 15/31/47/63 = row max
    v = dpp_fmax<0x142>(v);   // row_bcast:15 -> lane 31/63 = half max
    v = dpp_fmax<0x143>(v);   // row_bcast:31 -> lane 63 = wave max
    return v;
}

// Fused normalize + gram (+ DnT transpose for the store-phase vector gathers).
__global__ void k_ng(const float* __restrict__ D, float* __restrict__ Dn,
                     float* __restrict__ DnT, float* __restrict__ G,
                     double* __restrict__ loss_acc, unsigned int* __restrict__ ctr)
{
#pragma clang fp contract(off)
    __shared__ float nrmS[NEMB];
    __shared__ float coli[DIM];
    int i = blockIdx.x, j = threadIdx.x;
    if (i == 0 && j == 0) { loss_acc[0] = 0.0; ctr[0] = 0u; }
    float ss = 0.0f;
    for (int c = 0; c < DIM; c++) {
        float v = D[c * NEMB + j];
        float sq = v * v;
        ss = ss + sq;
    }
    float nrm = fmaxf(sqrtf(ss), 1e-10f);
    nrmS[j] = nrm;
    __syncthreads();
    if (j < DIM) {
        float dni = D[j * NEMB + i] / nrmS[i];
        coli[j] = dni;
        Dn[j * NEMB + i] = dni;         // block i owns Dn column i
        DnT[i * DIM + j] = dni;         // and DnT row i (same bits)
    }
    __syncthreads();
    float s = 0.0f;
#pragma unroll 8
    for (int c = 0; c < DIM; c++) {
        float dnj = D[c * NEMB + j] / nrm;     // rounds identically to Dn[c][j]
        s = fmaf(coli[c], dnj, s);
    }
    G[i * NEMB + j] = s;
}

// mu-law quantize+decode, all fp32, numpy op-for-op (no fusion)
__device__ __forceinline__ float quant_decode(float coeff)
{
#pragma clang fp contract(off)
    float c = fminf(fmaxf(coeff, -3.0f), 3.0f) / 3.0f;
    float ac = fabsf(c);
    float sgn = (c > 0.0f) ? 1.0f : ((c < 0.0f) ? -1.0f : 0.0f);
    float l = log1pf(ac * 50.0f);
    float enc = (sgn * l) * INV_MU_F;
    float scaled = (enc + 1.0f) * 7.5f;
    int bin = (int)rintf(scaled);              // round-half-even == np.round
    bin = bin < 0 ? 0 : (bin > 15 ? 15 : bin);
    float t = (float)bin * TWO15_F;
    float zv = t - 1.0f;
    float az = fabsf(zv);
    float sz = (zv > 0.0f) ? 1.0f : ((zv < 0.0f) ? -1.0f : 0.0f);
    float e = expm1f(az / INV_MU_F);
    return (sz * (e / 50.0f)) * 3.0f;
}

// FOUR signals' OMP (K=4) per call, fully scalarized (no arrays anywhere:
// every piece of state is a named scalar or by-value f2 -> SROA cannot fail,
// nothing can reach scratch). Selection/residual distributed over all 64
// lanes (4 atoms/lane); Cholesky+solves run ONCE on quarter-selected
// operands (lanes 16m..16m+15 = signal m).
// G-row handling = round-1's PROVEN register-cache pattern on the quad:
//  - at each kk the 4 selected atoms' G rows are loaded once (float4/lane,
//    uniform base + 4*lane, issued before chol -> latency hidden) and kept
//    in named registers;
//  - Gs = G[Iv_j][idx] extracted from the cached rows via cndmask tree +
//    readlane (~30cy VALU) instead of an L2 load (~200cy) on the chol
//    critical path;
//  - the residual reuses the cached rows (kills R7's repeated row loads).
// Same G elements, same fp op order as all passing versions -> bit-identical.
__device__ __forceinline__ void omp_quad4(
    f2 sA0, f2 sA1, f2 sB0, f2 sB1, f2 sC0, f2 sC1, f2 sD0, f2 sD1,
    int lane, int qt,
    const float* __restrict__ G,
    float* __restrict__ xsv, int* __restrict__ qi, int s0)
{
#pragma clang fp contract(off)
    f2 hA0 = sA0, hA1 = sA1, hB0 = sB0, hB1 = sB1;
    f2 hC0 = sC0, hC1 = sC1, hD0 = sD0, hD1 = sD1;
    int m4A = 0, m4B = 0, m4C = 0, m4D = 0;
    f2 gA00, gA01, gA10, gA11, gA20, gA21;        // cached G rows, signal A
    f2 gB00, gB01, gB10, gB11, gB20, gB21;
    f2 gC00, gC01, gC10, gC11, gC20, gC21;
    f2 gD00, gD01, gD10, gD11, gD20, gD21;
    int iq0 = 0, iq1 = 0, iq2 = 0, iq3 = 0;       // quarter-selected support
    float L10, L11, L20, L21, L22, L30, L31, L32, L33;
    float y0, y1, y2, y3;
    float x0 = 0.f, x1 = 0.f, x2 = 0.f, x3 = 0.f;
#pragma unroll
    for (int kk = 0; kk < 4; kk++) {
        // ---- per-lane best of own 4 atoms (ascending j, strict >) x4 ----
        float aA0 = (m4A & 1) ? 0.f : fabsf(hA0[0]);
        float aA1 = (m4A & 2) ? 0.f : fabsf(hA0[1]);
        float aA2 = (m4A & 4) ? 0.f : fabsf(hA1[0]);
        float aA3 = (m4A & 8) ? 0.f : fabsf(hA1[1]);
        float bvA = aA0; int bjA = 0;
        if (aA1 > bvA) { bvA = aA1; bjA = 1; }
        if (aA2 > bvA) { bvA = aA2; bjA = 2; }
        if (aA3 > bvA) { bvA = aA3; bjA = 3; }
        float aB0 = (m4B & 1) ? 0.f : fabsf(hB0[0]);
        float aB1 = (m4B & 2) ? 0.f : fabsf(hB0[1]);
        float aB2 = (m4B & 4) ? 0.f : fabsf(hB1[0]);
        float aB3 = (m4B & 8) ? 0.f : fabsf(hB1[1]);
        float bvB = aB0; int bjB = 0;
        if (aB1 > bvB) { bvB = aB1; bjB = 1; }
        if (aB2 > bvB) { bvB = aB2; bjB = 2; }
        if (aB3 > bvB) { bvB = aB3; bjB = 3; }
        float aC0 = (m4C & 1) ? 0.f : fabsf(hC0[0]);
        float aC1 = (m4C & 2) ? 0.f : fabsf(hC0[1]);
        float aC2 = (m4C & 4) ? 0.f : fabsf(hC1[0]);
        float aC3 = (m4C & 8) ? 0.f : fabsf(hC1[1]);
        float bvC = aC0; int bjC = 0;
        if (aC1 > bvC) { bvC = aC1; bjC = 1; }
        if (aC2 > bvC) { bvC = aC2; bjC = 2; }
        if (aC3 > bvC) { bvC = aC3; bjC = 3; }
        float aD0 = (m4D & 1) ? 0.f : fabsf(hD0[0]);
        float aD1 = (m4D & 2) ? 0.f : fabsf(hD0[1]);
        float aD2 = (m4D & 4) ? 0.f : fabsf(hD1[0]);
        float aD3 = (m4D & 8) ? 0.f : fabsf(hD1[1]);
        float bvD = aD0; int bjD = 0;
        if (aD1 > bvD) { bvD = aD1; bjD = 1; }
        if (aD2 > bvD) { bvD = aD2; bjD = 2; }
        if (aD3 > bvD) { bvD = aD3; bjD = 3; }
        // ---- wave max (value only) x4, then first-lane tie-break ----
        float rA = wave_max_nn(bvA);
        float rB = wave_max_nn(bvB);
        float rC = wave_max_nn(bvC);
        float rD = wave_max_nn(bvD);
        float vmA = rdlane_f(rA, 63), vmB = rdlane_f(rB, 63);
        float vmC = rdlane_f(rC, 63), vmD = rdlane_f(rD, 63);
        unsigned long long blA = __ballot(bvA == vmA);
        unsigned long long blB = __ballot(bvB == vmB);
        unsigned long long blC = __ballot(bvC == vmC);
        unsigned long long blD = __ballot(bvD == vmD);
        int owA = __ffsll((long long)blA) - 1;
        int owB = __ffsll((long long)blB) - 1;
        int owC = __ffsll((long long)blC) - 1;
        int owD = __ffsll((long long)blD) - 1;
        int boA = __builtin_amdgcn_readlane(bjA, owA);
        int boB = __builtin_amdgcn_readlane(bjB, owB);
        int boC = __builtin_amdgcn_readlane(bjC, owC);
        int boD = __builtin_amdgcn_readlane(bjD, owD);
        int idA = 4 * owA + boA;       // uniform
        int idB = 4 * owB + boB;
        int idC = 4 * owC + boC;
        int idD = 4 * owD + boD;
        m4A |= (lane == owA) ? (1 << boA) : 0;
        m4B |= (lane == owB) ? (1 << boB) : 0;
        m4C |= (lane == owC) ? (1 << boC) : 0;
        m4D |= (lane == owD) ? (1 << boD) : 0;
        // ---- original h_bar at selected atom ----
        float tvA = sA0[0];
        tvA = (bjA == 1) ? sA0[1] : tvA;
        tvA = (bjA == 2) ? sA1[0] : tvA;
        tvA = (bjA == 3) ? sA1[1] : tvA;
        float tvB = sB0[0];
        tvB = (bjB == 1) ? sB0[1] : tvB;
        tvB = (bjB == 2) ? sB1[0] : tvB;
        tvB = (bjB == 3) ? sB1[1] : tvB;
        float tvC = sC0[0];
        tvC = (bjC == 1) ? sC0[1] : tvC;
        tvC = (bjC == 2) ? sC1[0] : tvC;
        tvC = (bjC == 3) ? sC1[1] : tvC;
        float tvD = sD0[0];
        tvD = (bjD == 1) ? sD0[1] : tvD;
        tvD = (bjD == 2) ? sD1[0] : tvD;
        tvD = (bjD == 3) ? sD1[1] : tvD;
        float hsA = rdlane_f(tvA, owA);
        float hsB = rdlane_f(tvB, owB);
        float hsC = rdlane_f(tvC, owC);
        float hsD = rdlane_f(tvD, owD);
        float hsel = (qt & 2) ? ((qt & 1) ? hsD : hsC) : ((qt & 1) ? hsB : hsA);
        int idxq = (qt & 2) ? ((qt & 1) ? idD : idC) : ((qt & 1) ? idB : idA);
        if (kk == 0) iq0 = idxq;
        if (kk == 1) iq1 = idxq;
        if (kk == 2) iq2 = idxq;
        if (kk == 3) iq3 = idxq;
        // ---- cache this round's G rows (issued early, consumed in residual) ----
        const int l4 = 4 * lane;
        if (kk < 3) {
            float4 ra = *(const float4*)(G + ((size_t)idA << 8) + l4);
            float4 rb = *(const float4*)(G + ((size_t)idB << 8) + l4);
            float4 rc = *(const float4*)(G + ((size_t)idC << 8) + l4);
            float4 rd = *(const float4*)(G + ((size_t)idD << 8) + l4);
            if (kk == 0) {
                gA00 = (f2){ra.x, ra.y}; gA01 = (f2){ra.z, ra.w};
                gB00 = (f2){rb.x, rb.y}; gB01 = (f2){rb.z, rb.w};
                gC00 = (f2){rc.x, rc.y}; gC01 = (f2){rc.z, rc.w};
                gD00 = (f2){rd.x, rd.y}; gD01 = (f2){rd.z, rd.w};
            }
            if (kk == 1) {
                gA10 = (f2){ra.x, ra.y}; gA11 = (f2){ra.z, ra.w};
                gB10 = (f2){rb.x, rb.y}; gB11 = (f2){rb.z, rb.w};
                gC10 = (f2){rc.x, rc.y}; gC11 = (f2){rc.z, rc.w};
                gD10 = (f2){rd.x, rd.y}; gD11 = (f2){rd.z, rd.w};
            }
            if (kk == 2) {
                gA20 = (f2){ra.x, ra.y}; gA21 = (f2){ra.z, ra.w};
                gB20 = (f2){rb.x, rb.y}; gB21 = (f2){rb.z, rb.w};
                gC20 = (f2){rc.x, rc.y}; gC21 = (f2){rc.z, rc.w};
                gD20 = (f2){rd.x, rd.y}; gD21 = (f2){rd.z, rd.w};
            }
        }
        // ---- Gs = G[Iv_j][idx] by in-register extraction (no memory) ----
        float Gs0 = 0.f, Gs1 = 0.f, Gs2 = 0.f;
        if (kk > 0) {
            float eA = gA00[0];
            eA = (boA == 1) ? gA00[1] : eA;
            eA = (boA == 2) ? gA01[0] : eA;
            eA = (boA == 3) ? gA01[1] : eA;
            float eB = gB00[0];
            eB = (boB == 1) ? gB00[1] : eB;
            eB = (boB == 2) ? gB01[0] : eB;
            eB = (boB == 3) ? gB01[1] : eB;
            float eC = gC00[0];
            eC = (boC == 1) ? gC00[1] : eC;
            eC = (boC == 2) ? gC01[0] : eC;
            eC = (boC == 3) ? gC01[1] : eC;
            float eD = gD00[0];
            eD = (boD == 1) ? gD00[1] : eD;
            eD = (boD == 2) ? gD01[0] : eD;
            eD = (boD == 3) ? gD01[1] : eD;
            float GsA = rdlane_f(eA, owA);
            float GsB = rdlane_f(eB, owB);
            float GsC = rdlane_f(eC, owC);
            float GsD = rdlane_f(eD, owD);
            Gs0 = (qt & 2) ? ((qt & 1) ? GsD : GsC) : ((qt & 1) ? GsB : GsA);
        }
        if (kk > 1) {
            float eA = gA10[0];
            eA = (boA == 1) ? gA10[1] : eA;
            eA = (boA == 2) ? gA11[0] : eA;
            eA = (boA == 3) ? gA11[1] : eA;
            float eB = gB10[0];
            eB = (boB == 1) ? gB10[1] : eB;
            eB = (boB == 2) ? gB11[0] : eB;
            eB = (boB == 3) ? gB11[1] : eB;
            float eC = gC10[0];
            eC = (boC == 1) ? gC10[1] : eC;
            eC = (boC == 2) ? gC11[0] : eC;
            eC = (boC == 3) ? gC11[1] : eC;
            float eD = gD10[0];
            eD = (boD == 1) ? gD10[1] : eD;
            eD = (boD == 2) ? gD11[0] : eD;
            eD = (boD == 3) ? gD11[1] : eD;
            float GsA = rdlane_f(eA, owA);
            float GsB = rdlane_f(eB, owB);
            float GsC = rdlane_f(eC, owC);
            float GsD = rdlane_f(eD, owD);
            Gs1 = (qt & 2) ? ((qt & 1) ? GsD : GsC) : ((qt & 1) ? GsB : GsA);
        }
        if (kk > 2) {
            float eA = gA20[0];
            eA = (boA == 1) ? gA20[1] : eA;
            eA = (boA == 2) ? gA21[0] : eA;
            eA = (boA == 3) ? gA21[1] : eA;
            float eB = gB20[0];
            eB = (boB == 1) ? gB20[1] : eB;
            eB = (boB == 2) ? gB21[0] : eB;
            eB = (boB == 3) ? gB21[1] : eB;
            float eC = gC20[0];
            eC = (boC == 1) ? gC20[1] : eC;
            eC = (boC == 2) ? gC21[0] : eC;
            eC = (boC == 3) ? gC21[1] : eC;
            float eD = gD20[0];
            eD = (boD == 1) ? gD20[1] : eD;
            eD = (boD == 2) ? gD21[0] : eD;
            eD = (boD == 3) ? gD21[1] : eD;
            float GsA = rdlane_f(eA, owA);
            float GsB = rdlane_f(eB, owB);
            float GsC = rdlane_f(eC, owC);
            float GsD = rdlane_f(eD, owD);
            Gs2 = (qt & 2) ? ((qt & 1) ? GsD : GsC) : ((qt & 1) ? GsB : GsA);
        }
        // ---- Cholesky row update (verbatim; /L00==1 removed, exact) ----
        if (kk == 1) {
            float cw0 = Gs0;
            float css = cw0 * cw0;
            float om = 1.0f - css;
            L10 = cw0;
            L11 = sqrtf(fmaxf(om, 1e-12f));
        }
        if (kk == 2) {
            float cw0 = Gs0;
            float ct = Gs1 - L10 * cw0;
            float cw1 = ct / L11;
            float css = cw0 * cw0;
            float cp = cw1 * cw1; css = css + cp;
            float om = 1.0f - css;
            L20 = cw0; L21 = cw1;
            L22 = sqrtf(fmaxf(om, 1e-12f));
        }
        if (kk == 3) {
            float cw0 = Gs0;
            float ct = Gs1 - L10 * cw0;
            float cw1 = ct / L11;
            float ca = L20 * cw0;
            float cp = L21 * cw1; ca = ca + cp;
            float ct3 = Gs2 - ca;
            float cw2 = ct3 / L22;
            float css = cw0 * cw0;
            cp = cw1 * cw1; css = css + cp;
            cp = cw2 * cw2; css = css + cp;
            float om = 1.0f - css;
            L30 = cw0; L31 = cw1; L32 = cw2;
            L33 = sqrtf(fmaxf(om, 1e-12f));
        }
        // ---- forward solve, incremental (row kk only) ----
        if (kk == 0) y0 = hsel;
        if (kk == 1) { float a = L10 * y0; y1 = (hsel - a) / L11; }
        if (kk == 2) { float a = L20 * y0; float p = L21 * y1; a = a + p;
                       y2 = (hsel - a) / L22; }
        if (kk == 3) { float a = L30 * y0; float p = L31 * y1; a = a + p;
                       p = L32 * y2; a = a + p;
                       y3 = (hsel - a) / L33; }
        // ---- backward solve L^T x = y (full, cc ascending) ----
        if (kk == 0) { x0 = y0; }
        if (kk == 1) {
            x1 = y1 / L11;
            float a = L10 * x1;
            x0 = y0 - a;
        }
        if (kk == 2) {
            x2 = y2 / L22;
            float a = L21 * x2;
            x1 = (y1 - a) / L11;
            a = L10 * x1;
            float p = L20 * x2; a = a + p;
            x0 = y0 - a;
        }
        if (kk == 3) {
            x3 = y3 / L33;
            float a = L32 * x3;
            x2 = (y2 - a) / L22;
            a = L21 * x2;
            float p = L31 * x3; a = a + p;
            x1 = (y1 - a) / L11;
            a = L10 * x1;
            p = L20 * x2; a = a + p;
            p = L30 * x3; a = a + p;
            x0 = y0 - a;
        }
        // ---- residual from cached rows (mul+add ascending j) ----
        if (kk < 3) {
            float xbA0 = rdlane_f(x0, 0),  xbB0 = rdlane_f(x0, 16);
            float xbC0 = rdlane_f(x0, 32), xbD0 = rdlane_f(x0, 48);
            float xbA1 = 0.f, xbB1 = 0.f, xbC1 = 0.f, xbD1 = 0.f;
            float xbA2 = 0.f, xbB2 = 0.f, xbC2 = 0.f, xbD2 = 0.f;
            if (kk > 0) { xbA1 = rdlane_f(x1, 0);  xbB1 = rdlane_f(x1, 16);
                          xbC1 = rdlane_f(x1, 32); xbD1 = rdlane_f(x1, 48); }
            if (kk > 1) { xbA2 = rdlane_f(x2, 0);  xbB2 = rdlane_f(x2, 16);
                          xbC2 = rdlane_f(x2, 32); xbD2 = rdlane_f(x2, 48); }
            {   // signal A
                f2 bsa = (f2){xbA0, xbA0} * gA00;
                f2 bsb = (f2){xbA0, xbA0} * gA01;
                if (kk > 0) { f2 pa = (f2){xbA1, xbA1} * gA10; bsa = bsa + pa;
                              f2 pb = (f2){xbA1, xbA1} * gA11; bsb = bsb + pb; }
                if (kk > 1) { f2 pa = (f2){xbA2, xbA2} * gA20; bsa = bsa + pa;
                              f2 pb = (f2){xbA2, xbA2} * gA21; bsb = bsb + pb; }
                hA0 = sA0 - bsa;
                hA1 = sA1 - bsb;
            }
            {   // signal B
                f2 bsa = (f2){xbB0, xbB0} * gB00;
                f2 bsb = (f2){xbB0, xbB0} * gB01;
                if (kk > 0) { f2 pa = (f2){xbB1, xbB1} * gB10; bsa = bsa + pa;
                              f2 pb = (f2){xbB1, xbB1} * gB11; bsb = bsb + pb; }
                if (kk > 1) { f2 pa = (f2){xbB2, xbB2} * gB20; bsa = bsa + pa;
                              f2 pb = (f2){xbB2, xbB2} * gB21; bsb = bsb + pb; }
                hB0 = sB0 - bsa;
                hB1 = sB1 - bsb;
            }
            {   // signal C
                f2 bsa = (f2){xbC0, xbC0} * gC00;
                f2 bsb = (f2){xbC0, xbC0} * gC01;
                if (kk > 0) { f2 pa = (f2){xbC1, xbC1} * gC10; bsa = bsa + pa;
                              f2 pb = (f2){xbC1, xbC1} * gC11; bsb = bsb + pb; }
                if (kk > 1) { f2 pa = (f2){xbC2, xbC2} * gC20; bsa = bsa + pa;
                              f2 pb = (f2){xbC2, xbC2} * gC21; bsb = bsb + pb; }
                hC0 = sC0 - bsa;
                hC1 = sC1 - bsb;
            }
            {   // signal D
                f2 bsa = (f2){xbD0, xbD0} * gD00;
                f2 bsb = (f2){xbD0, xbD0} * gD01;
                if (kk > 0) { f2 pa = (f2){xbD1, xbD1} * gD10; bsa = bsa + pa;
                              f2 pb = (f2){xbD1, xbD1} * gD11; bsb = bsb + pb; }
                if (kk > 1) { f2 pa = (f2){xbD2, xbD2} * gD20; bsa = bsa + pa;
                              f2 pb = (f2){xbD2, xbD2} * gD21; bsb = bsb + pb; }
                hD0 = sD0 - bsa;
                hD1 = sD1 - bsb;
            }
        }
    }
    // quarter-lead lanes (0,16,32,48) write their signal's coeffs + support
    if ((lane & 15) == 0) {
        int s = s0 + qt;
        xsv[0 * SIGS_B + s] = x0; xsv[1 * SIGS_B + s] = x1;
        xsv[2 * SIGS_B + s] = x2; xsv[3 * SIGS_B + s] = x3;
        qi[0 * SIGS_B + s] = iq0; qi[1 * SIGS_B + s] = iq1;
        qi[2 * SIGS_B + s] = iq2; qi[3 * SIGS_B + s] = iq3;
    }
}

// __launch_bounds__(256, 2): min 2 waves/EU -> VGPR cap 256. The allocator
// has consistently chosen HALF the cap (128->64, 85->40, 64->32, rounds
// 1-8), spilling the OMP working set as scratch (~65MB/launch excess HBM
// writes). Cap 256 -> expected ~128-VGPR allocation = working set fits.
// 128 VGPR still gives 4 waves/SIMD = 16 waves/CU, above the observed 12.
__launch_bounds__(THREADS, 2)
__global__ void k_omp(const float* __restrict__ z,
                      const float* __restrict__ Dn_g,
                      const float* __restrict__ DnT_g,
                      const float* __restrict__ G,
                      double* __restrict__ loss_acc,
                      unsigned int* __restrict__ ctr,
                      float* __restrict__ zq,
                      float* __restrict__ loss_out)
{
    extern __shared__ char smem[];
    float* sig = (float*)(smem + LB_SIG);
    float* xsv = (float*)(smem + LB_XS);
    int* qi = (int*)(smem + LB_QI);
    double* red = (double*)(smem + LB_RED);

    int tid = threadIdx.x;
    int lane = tid & 63;
    int qt = lane >> 4;          // lane quarter = signal slot within quad
    int wid = tid >> 6;          // 0..3

    long sbase = (long)blockIdx.x * SIGS_B;  // 64 consecutive pixels, one batch b
    int b = (int)(sbase >> 12);
    int pl0 = (int)(sbase & 4095);
    const float* zb = z + ((size_t)b << 18) + pl0;
    // stage z_e -> sig[c][w], coalesced along w
    {
        int w = tid & (SIGS_B - 1);
        int g = tid >> 6;
#pragma unroll
        for (int i = 0; i < 16; i++) {
            int c = g * 16 + i;
            sig[c * SIGS_B + w] = zb[(size_t)c * 4096 + w];
        }
    }
    __syncthreads();

    // each wave: 16 signals in 2 groups of 8; h_bar = X^T Dn, fp32 fused-FMA
    // sequential over c ascending, packed as float2 -> v_pk_fma_f32.
    // h_bar fragments are NAMED f2 scalars (no array -> no scratch risk).
    for (int g2 = 0; g2 < 2; g2++) {
        int s0 = wid * 16 + g2 * 8;
        f2 h00 = {0.f, 0.f}, h01 = {0.f, 0.f};
        f2 h10 = {0.f, 0.f}, h11 = {0.f, 0.f};
        f2 h20 = {0.f, 0.f}, h21 = {0.f, 0.f};
        f2 h30 = {0.f, 0.f}, h31 = {0.f, 0.f};
        f2 h40 = {0.f, 0.f}, h41 = {0.f, 0.f};
        f2 h50 = {0.f, 0.f}, h51 = {0.f, 0.f};
        f2 h60 = {0.f, 0.f}, h61 = {0.f, 0.f};
        f2 h70 = {0.f, 0.f}, h71 = {0.f, 0.f};
#pragma unroll 8
        for (int c = 0; c < DIM; c++) {
            float4 sva = *(const float4*)(sig + c * SIGS_B + s0);
            float4 svb = *(const float4*)(sig + c * SIGS_B + s0 + 4);
            float4 dv = *(const float4*)(Dn_g + c * NEMB + 4 * lane);
            f2 d0 = {dv.x, dv.y};
            f2 d1 = {dv.z, dv.w};
            h00 = __builtin_elementwise_fma((f2){sva.x, sva.x}, d0, h00);
            h01 = __builtin_elementwise_fma((f2){sva.x, sva.x}, d1, h01);
            h10 = __builtin_elementwise_fma((f2){sva.y, sva.y}, d0, h10);
            h11 = __builtin_elementwise_fma((f2){sva.y, sva.y}, d1, h11);
            h20 = __builtin_elementwise_fma((f2){sva.z, sva.z}, d0, h20);
            h21 = __builtin_elementwise_fma((f2){sva.z, sva.z}, d1, h21);
            h30 = __builtin_elementwise_fma((f2){sva.w, sva.w}, d0, h30);
            h31 = __builtin_elementwise_fma((f2){sva.w, sva.w}, d1, h31);
            h40 = __builtin_elementwise_fma((f2){svb.x, svb.x}, d0, h40);
            h41 = __builtin_elementwise_fma((f2){svb.x, svb.x}, d1, h41);
            h50 = __builtin_elementwise_fma((f2){svb.y, svb.y}, d0, h50);
            h51 = __builtin_elementwise_fma((f2){svb.y, svb.y}, d1, h51);
            h60 = __builtin_elementwise_fma((f2){svb.z, svb.z}, d0, h60);
            h61 = __builtin_elementwise_fma((f2){svb.z, svb.z}, d1, h61);
            h70 = __builtin_elementwise_fma((f2){svb.w, svb.w}, d0, h70);
            h71 = __builtin_elementwise_fma((f2){svb.w, svb.w}, d1, h71);
        }
        omp_quad4(h00, h01, h10, h11, h20, h21, h30, h31,
                  lane, qt, G, xsv, qi, s0);
        omp_quad4(h40, h41, h50, h51, h60, h61, h70, h71,
                  lane, qt, G, xsv, qi, s0 + 4);
    }
    __syncthreads();

    // thread-parallel mu-law quantize of all 256 coeffs (one per thread)
    {
        int jq = tid >> 6;
        int wq = tid & (SIGS_B - 1);
        xsv[jq * SIGS_B + wq] = quant_decode(xsv[jq * SIGS_B + wq]);
    }
    __syncthreads();

    // store phase: recon (einsum order: mul+add, k ascending, no fma),
    // gathers vectorized via DnT (DnT[i][c] == Dn[c][i], bit-identical).
    double lsum = 0.0;
    float* zqb = zq + ((size_t)b << 18) + pl0;
    {
#pragma clang fp contract(off)
        int w = tid & (SIGS_B - 1);
        int g = tid >> 6;
        float q0 = xsv[0 * SIGS_B + w], q1 = xsv[1 * SIGS_B + w];
        float q2 = xsv[2 * SIGS_B + w], q3 = xsv[3 * SIGS_B + w];
        int i0 = qi[0 * SIGS_B + w], i1 = qi[1 * SIGS_B + w];
        int i2 = qi[2 * SIGS_B + w], i3 = qi[3 * SIGS_B + w];
        const float* t0p = DnT_g + (i0 << 6) + (g << 4);
        const float* t1p = DnT_g + (i1 << 6) + (g << 4);
        const float* t2p = DnT_g + (i2 << 6) + (g << 4);
        const float* t3p = DnT_g + (i3 << 6) + (g << 4);
#pragma unroll
        for (int cb = 0; cb < 4; cb++) {
            float4 d0 = *(const float4*)(t0p + 4 * cb);
            float4 d1 = *(const float4*)(t1p + 4 * cb);
            float4 d2 = *(const float4*)(t2p + 4 * cb);
            float4 d3 = *(const float4*)(t3p + 4 * cb);
#pragma unroll
            for (int u = 0; u < 4; u++) {
                int c = (g << 4) + (cb << 2) + u;
                float e0 = (u == 0) ? d0.x : (u == 1) ? d0.y : (u == 2) ? d0.z : d0.w;
                float e1 = (u == 0) ? d1.x : (u == 1) ? d1.y : (u == 2) ? d1.z : d1.w;
                float e2 = (u == 0) ? d2.x : (u == 1) ? d2.y : (u == 2) ? d2.z : d2.w;
                float e3 = (u == 0) ? d3.x : (u == 1) ? d3.y : (u == 2) ? d3.z : d3.w;
                float p0 = q0 * e0;
                float p1 = q1 * e1;
                float p2 = q2 * e2;
                float p3 = q3 * e3;
                float r = p0 + p1;
                r = r + p2;
                r = r + p3;
                float zev = sig[c * SIGS_B + w];
                float d = r - zev;
                float zqv = zev + d;           // z_q = z_e + (recon - z_e)
                lsum += (double)d * (double)d;
                zqb[(size_t)c * 4096 + w] = zqv;
            }
        }
    }
#pragma unroll
    for (int off = 32; off > 0; off >>= 1) lsum += __shfl_xor(lsum, off);
    if (lane == 0) red[wid] = lsum;
    __syncthreads();
    if (tid == 0) {
        double t = 0.0;
#pragma unroll
        for (int i = 0; i < 4; i++) t += red[i];
        atomicAdd(loss_acc, t);
        __threadfence();
        unsigned int done = atomicAdd(ctr, 1u);
        if (done == GRID - 1) {
            double m = atomicAdd(loss_acc, 0.0) / 8388608.0;
            loss_out[0] = (float)(m + 0.25 * m);
        }
    }
}

extern "C" void kernel_launch(void* const* d_in, const int* in_sizes, int n_in,
                              void* d_out, int out_size, void* d_ws, size_t ws_size,
                              hipStream_t stream)
{
    const float* z = (const float*)d_in[0];
    const float* D = (const float*)d_in[1];
    float* out = (float*)d_out;
    char* ws = (char*)d_ws;
    double* loss_acc = (double*)ws;                       // 8 B
    unsigned int* ctr = (unsigned int*)(ws + 8);          // 4 B
    float* Dn = (float*)(ws + 256);                       // 64x256 f32
    float* G = (float*)(ws + 256 + 65536);                // 256x256 f32
    float* DnT = (float*)(ws + 256 + 65536 + 262144);     // 256x64 f32

    k_ng<<<NEMB, NEMB, 0, stream>>>(D, Dn, DnT, G, loss_acc, ctr);
    hipFuncSetAttribute(reinterpret_cast<const void*>(k_omp),
                        hipFuncAttributeMaxDynamicSharedMemorySize, LDS_BYTES);
    k_omp<<<GRID, THREADS, LDS_BYTES, stream>>>(z, Dn, DnT, G, loss_acc, ctr, out, out + 8388608);
    (void)in_sizes; (void)n_in; (void)out_size; (void)ws_size;
}